// Round 5
// baseline (471.382 us; speedup 1.0000x reference)
//
#include <hip/hip_runtime.h>
#include <cstdint>
#include <cstddef>

#define NN 50000
#define EE 640000
#define DD 128
#define LL 3
#define GG 256
#define LATD 64

typedef __attribute__((ext_vector_type(8))) __bf16 bf16x8;
typedef __attribute__((ext_vector_type(4))) float f32x4;

__device__ __forceinline__ unsigned short f2bf(float f) {
  __bf16 h = (__bf16)f;
  return __builtin_bit_cast(unsigned short, h);
}
__device__ __forceinline__ float bf2f(unsigned int u16) {
  unsigned int x = u16 << 16;
  return __builtin_bit_cast(float, x);
}
__device__ __forceinline__ void unpack8(uint4 v, float* f) {
  f[0] = bf2f(v.x & 0xffffu); f[1] = bf2f(v.x >> 16);
  f[2] = bf2f(v.y & 0xffffu); f[3] = bf2f(v.y >> 16);
  f[4] = bf2f(v.z & 0xffffu); f[5] = bf2f(v.z >> 16);
  f[6] = bf2f(v.w & 0xffffu); f[7] = bf2f(v.w >> 16);
}
__device__ __forceinline__ void acc8(uint4 v, float* f) {
  f[0] += bf2f(v.x & 0xffffu); f[1] += bf2f(v.x >> 16);
  f[2] += bf2f(v.y & 0xffffu); f[3] += bf2f(v.y >> 16);
  f[4] += bf2f(v.z & 0xffffu); f[5] += bf2f(v.z >> 16);
  f[6] += bf2f(v.w & 0xffffu); f[7] += bf2f(v.w >> 16);
}
__device__ __forceinline__ uint4 pack8(const float* f) {
  uint4 v;
  v.x = f2bf(f[0]) | ((unsigned)f2bf(f[1]) << 16);
  v.y = f2bf(f[2]) | ((unsigned)f2bf(f[3]) << 16);
  v.z = f2bf(f[4]) | ((unsigned)f2bf(f[5]) << 16);
  v.w = f2bf(f[6]) | ((unsigned)f2bf(f[7]) << 16);
  return v;
}

#define SWZ(byte_, row_) ((byte_) ^ (((row_) & 7) << 4))

// ---------- prep: x cvt | weights cvt pre-swizzled | degree hist ----------
#define CVT_BLK 3125   // 800000 threads exact
#define WCV_BLK 48     // 12288 threads exact
#define HIST_BLK 2500  // 640000 threads exact
__global__ __launch_bounds__(256) void prep_kernel(
    const float4* __restrict__ x, uint4* __restrict__ xb,
    const float* __restrict__ W1, const float* __restrict__ W2,
    uint4* __restrict__ wb, const int* __restrict__ dst,
    int* __restrict__ counts) {
  int b = blockIdx.x;
  if (b < CVT_BLK) {
    int t = b * 256 + threadIdx.x;
    float4 a = x[t * 2], bb = x[t * 2 + 1];
    float f[8] = {a.x, a.y, a.z, a.w, bb.x, bb.y, bb.z, bb.w};
    xb[t] = pack8(f);
  } else if (b < CVT_BLK + WCV_BLK) {
    int t = (b - CVT_BLK) * 256 + threadIdx.x;
    int m = t >> 11;            // matrix 0..5
    int q = t & 2047;           // 16B chunk
    int byte = q * 16;
    int row = byte >> 8;
    int inner = byte & 255;
    int isrc = inner ^ ((row & 7) << 4);   // inverse swizzle (involution)
    int k0 = isrc >> 1;
    const float* Wsrc = (m & 1) ? W2 : W1;
    const float* p = Wsrc + ((size_t)(m >> 1) * DD * DD + row * DD + k0);
    float4 f0 = ((const float4*)p)[0], f1 = ((const float4*)p)[1];
    float f[8] = {f0.x, f0.y, f0.z, f0.w, f1.x, f1.y, f1.z, f1.w};
    wb[(size_t)m * 2048 + q] = pack8(f);
  } else {
    int e = (b - CVT_BLK - WCV_BLK) * 256 + threadIdx.x;
    atomicAdd(&counts[dst[e]], 1);
  }
}

// ---------- CSR scans (+ degree-bucket machinery fused in) ----------
__global__ __launch_bounds__(256) void scan1_kernel(const int* __restrict__ counts,
                                                    int* __restrict__ rp,
                                                    int* __restrict__ bsum,
                                                    int* __restrict__ binCnt, int n) {
  __shared__ int lbin[64];
  if (threadIdx.x < 64) lbin[threadIdx.x] = 0;
  __syncthreads();
  int i = blockIdx.x * 256 + threadIdx.x;
  int v = (i < n) ? counts[i] : 0;
  if (i < n) atomicAdd(&lbin[v > 63 ? 63 : v], 1);
  int lane = threadIdx.x & 63, w = threadIdx.x >> 6;
  int s = v;
#pragma unroll
  for (int off = 1; off < 64; off <<= 1) {
    int u = __shfl_up(s, off);
    if (lane >= off) s += u;
  }
  __shared__ int ws[4];
  if (lane == 63) ws[w] = s;
  __syncthreads();
  int add = 0;
#pragma unroll
  for (int k = 0; k < 4; ++k) if (k < w) add += ws[k];
  int incl = s + add;
  if (i < n) rp[i] = incl - v;
  if (threadIdx.x == 255) bsum[blockIdx.x] = incl;
  if (threadIdx.x < 64 && lbin[threadIdx.x] > 0)
    atomicAdd(&binCnt[threadIdx.x], lbin[threadIdx.x]);
}

__global__ __launch_bounds__(256) void scan2_kernel(int* __restrict__ bsum, int nb,
                                                    const int* __restrict__ binCnt,
                                                    int* __restrict__ binCursor) {
  int t = threadIdx.x;
  int v = (t < nb) ? bsum[t] : 0;
  int lane = t & 63, w = t >> 6;
  int s = v;
#pragma unroll
  for (int off = 1; off < 64; off <<= 1) {
    int u = __shfl_up(s, off);
    if (lane >= off) s += u;
  }
  __shared__ int ws[4];
  if (lane == 63) ws[w] = s;
  __syncthreads();
  int add = 0;
#pragma unroll
  for (int k = 0; k < 4; ++k) if (k < w) add += ws[k];
  int incl = s + add;
  if (t < nb) bsum[t] = incl - v;
  // 64-bin exclusive scan for degree buckets (wave 0)
  if (t < 64) {
    int bv = binCnt[t];
    int bs = bv;
#pragma unroll
    for (int off = 1; off < 64; off <<= 1) {
      int u = __shfl_up(bs, off);
      if (lane >= off) bs += u;
    }
    binCursor[t] = bs - bv;
  }
}

__global__ __launch_bounds__(256) void scan3_kernel(int* __restrict__ rp,
                                                    int* __restrict__ cursor,
                                                    const int* __restrict__ bsum,
                                                    const int* __restrict__ counts,
                                                    int* __restrict__ binCursor,
                                                    int* __restrict__ perm, int n) {
  int i = blockIdx.x * 256 + threadIdx.x;
  if (i < n) {
    int v = rp[i] + bsum[blockIdx.x];
    rp[i] = v;
    cursor[i] = v;
    int bkt = counts[i]; if (bkt > 63) bkt = 63;
    int pos = atomicAdd(&binCursor[bkt], 1);
    perm[pos] = i;
  }
  if (i == 0) rp[n] = EE;
}

__global__ __launch_bounds__(256) void fill_kernel(const int* __restrict__ src,
                                                   const int* __restrict__ dst,
                                                   int* __restrict__ cursor,
                                                   int* __restrict__ col, int E) {
  int e = blockIdx.x * blockDim.x + threadIdx.x;
  if (e < E) {
    int p = atomicAdd(&cursor[dst[e]], 1);
    col[p] = src[e];
  }
}

// ---------- GIN aggregation: degree-sorted, 8-deep ILP, swizzled output ----------
__global__ __launch_bounds__(256, 8) void agg_kernel(const uint4* __restrict__ xin,
                                                     const int* __restrict__ row_ptr,
                                                     const int* __restrict__ colv,
                                                     const int* __restrict__ perm,
                                                     char* __restrict__ aggsw, int n) {
  int tid = blockIdx.x * 256 + threadIdx.x;
  int grp = tid >> 4;
  int c = tid & 15;
  if (grp >= n) return;
  int node = perm[grp];
  float acc[8];
  unpack8(xin[(size_t)node * 16 + c], acc);
  int s = row_ptr[node], e = row_ptr[node + 1];
  int j = s;
  for (; j + 8 <= e; j += 8) {
    int4 i0 = *(const int4*)(colv + j);
    int4 i1 = *(const int4*)(colv + j + 4);   // colv 16B-aligned only per j... use element loads
    uint4 v0 = xin[(size_t)i0.x * 16 + c];
    uint4 v1 = xin[(size_t)i0.y * 16 + c];
    uint4 v2 = xin[(size_t)i0.z * 16 + c];
    uint4 v3 = xin[(size_t)i0.w * 16 + c];
    uint4 v4 = xin[(size_t)i1.x * 16 + c];
    uint4 v5 = xin[(size_t)i1.y * 16 + c];
    uint4 v6 = xin[(size_t)i1.z * 16 + c];
    uint4 v7 = xin[(size_t)i1.w * 16 + c];
    acc8(v0, acc); acc8(v1, acc); acc8(v2, acc); acc8(v3, acc);
    acc8(v4, acc); acc8(v5, acc); acc8(v6, acc); acc8(v7, acc);
  }
  for (; j + 2 <= e; j += 2) {
    uint4 v0 = xin[(size_t)colv[j] * 16 + c];
    uint4 v1 = xin[(size_t)colv[j + 1] * 16 + c];
    acc8(v0, acc); acc8(v1, acc);
  }
  if (j < e) acc8(xin[(size_t)colv[j] * 16 + c], acc);
  unsigned byte = (unsigned)node * 256 + ((c * 16) ^ ((node & 7) << 4));
  *(uint4*)(aggsw + byte) = pack8(acc);
}

// ---------- MFMA MLP: 64-row tile, 80KB LDS; optional fused pooling ----------
template <bool POOL>
__global__ __launch_bounds__(256) void mlp64(
    const uint4* __restrict__ aggsw, unsigned short* __restrict__ xout,
    const uint4* __restrict__ w1b, const uint4* __restrict__ w2b,
    const float* __restrict__ b1, const float* __restrict__ bng,
    const float* __restrict__ bnb, const float* __restrict__ bnm,
    const float* __restrict__ bnv, const float* __restrict__ b2,
    const int* __restrict__ batch, float* __restrict__ pooled, int n) {
  __shared__ __align__(16) char smem[81920];
  char* w1p = smem;           // 32KB bf16 W1, pre-swizzled (reused as pool partials)
  char* w2p = smem + 32768;   // 32KB bf16 W2
  char* xp  = smem + 65536;   // 16KB: 64 rows x 256B, pre-swizzled in global

#pragma unroll
  for (int it = 0; it < 8; ++it) {
    int q = it * 256 + threadIdx.x;
    ((uint4*)w1p)[q] = w1b[q];
    ((uint4*)w2p)[q] = w2b[q];
  }
  int base = blockIdx.x * 64;
#pragma unroll
  for (int it = 0; it < 4; ++it) {
    int q = it * 256 + threadIdx.x;   // 1024 chunks of 16B, linear (pre-swizzled)
    int grow = base + (q >> 4);
    uint4 v = make_uint4(0, 0, 0, 0);
    if (grow < n) v = aggsw[(size_t)base * 16 + q];
    ((uint4*)xp)[q] = v;
  }
  __syncthreads();

  int lane = threadIdx.x & 63;
  int c = lane & 15;
  int kq = lane >> 4;
  int wave = threadIdx.x >> 6;
  int r0 = wave * 16;

  float b1v[8], sv[8], tv[8], b2v[8];
#pragma unroll
  for (int ni = 0; ni < 8; ++ni) {
    int cc = ni * 16 + c;
    b1v[ni] = b1[cc];
    float s = bng[cc] * rsqrtf(bnv[cc] + 1e-5f);
    sv[ni] = s;
    tv[ni] = bnb[cc] - bnm[cc] * s;
    b2v[ni] = b2[cc];
  }

  f32x4 acc[8];
#pragma unroll
  for (int ni = 0; ni < 8; ++ni) acc[ni] = (f32x4){0.f, 0.f, 0.f, 0.f};

  // GEMM1: h = X @ W1^T
#pragma unroll
  for (int ks = 0; ks < 4; ++ks) {
    int row = r0 + c;
    bf16x8 a = *(const bf16x8*)(xp + SWZ(row * 256 + ks * 64 + kq * 16, row));
#pragma unroll
    for (int ni = 0; ni < 8; ++ni) {
      int wr = ni * 16 + c;
      bf16x8 bfr = *(const bf16x8*)(w1p + SWZ(wr * 256 + ks * 64 + kq * 16, wr));
      acc[ni] = __builtin_amdgcn_mfma_f32_16x16x32_bf16(a, bfr, acc[ni], 0, 0, 0);
    }
  }

  // epilogue 1: leaky + BN -> back to X LDS (wave-local rows)
#pragma unroll
  for (int ni = 0; ni < 8; ++ni)
#pragma unroll
    for (int r = 0; r < 4; ++r) {
      float h = acc[ni][r] + b1v[ni];
      h = h >= 0.f ? h : 0.2f * h;
      h = h * sv[ni] + tv[ni];
      int row = r0 + kq * 4 + r;
      *(__bf16*)(xp + SWZ(row * 256 + (ni * 16 + c) * 2, row)) = (__bf16)h;
    }
  __syncthreads();   // all GEMM1 w1p reads + epi1 xp writes complete

  if (POOL) {
    float* part = (float*)w1p;   // 8 slots x 128 dims
#pragma unroll
    for (int k = 0; k < 4; ++k) part[k * 256 + threadIdx.x] = 0.f;
    __syncthreads();
  }

#pragma unroll
  for (int ni = 0; ni < 8; ++ni) acc[ni] = (f32x4){0.f, 0.f, 0.f, 0.f};

  // GEMM2: x = h @ W2^T
#pragma unroll
  for (int ks = 0; ks < 4; ++ks) {
    int row = r0 + c;
    bf16x8 a = *(const bf16x8*)(xp + SWZ(row * 256 + ks * 64 + kq * 16, row));
#pragma unroll
    for (int ni = 0; ni < 8; ++ni) {
      int wr = ni * 16 + c;
      bf16x8 bfr = *(const bf16x8*)(w2p + SWZ(wr * 256 + ks * 64 + kq * 16, wr));
      acc[ni] = __builtin_amdgcn_mfma_f32_16x16x32_bf16(a, bfr, acc[ni], 0, 0, 0);
    }
  }

  // epilogue 2
  if (POOL) {
    int gb = batch[base];
    float* part = (float*)w1p;
#pragma unroll
    for (int r = 0; r < 4; ++r) {
      int grow = base + r0 + kq * 4 + r;
      if (grow < n) {
        int slot = batch[grow] - gb;
#pragma unroll
        for (int ni = 0; ni < 8; ++ni) {
          float xo = acc[ni][r] + b2v[ni];
          xo = xo >= 0.f ? xo : 0.2f * xo;
          if (slot < 8) atomicAdd(&part[slot * DD + ni * 16 + c], xo);
          else atomicAdd(&pooled[(size_t)(gb + slot) * DD + ni * 16 + c], xo);
        }
      }
    }
    __syncthreads();
#pragma unroll
    for (int k = 0; k < 4; ++k) {
      int idx = k * 256 + threadIdx.x;      // 0..1023
      float v = part[idx];
      if (v != 0.f)
        atomicAdd(&pooled[(size_t)(gb + (idx >> 7)) * DD + (idx & 127)], v);
    }
  } else {
#pragma unroll
    for (int ni = 0; ni < 8; ++ni)
#pragma unroll
      for (int r = 0; r < 4; ++r) {
        float xo = acc[ni][r] + b2v[ni];
        xo = xo >= 0.f ? xo : 0.2f * xo;
        int grow = base + r0 + kq * 4 + r;
        if (grow < n) xout[(size_t)grow * DD + ni * 16 + c] = f2bf(xo);
      }
  }
}

// ---------- head ----------
__global__ __launch_bounds__(128) void head_kernel(const float* __restrict__ pooled,
    const float* __restrict__ og, const float* __restrict__ ob,
    const float* __restrict__ om, const float* __restrict__ ov,
    const float* __restrict__ fcW, const float* __restrict__ fcb,
    float* __restrict__ out) {
  __shared__ float pb[DD];
  int g = blockIdx.x;
  int t = threadIdx.x;
  float s = og[t] * rsqrtf(ov[t] + 1e-5f);
  pb[t] = (pooled[(size_t)g * DD + t] - om[t]) * s + ob[t];
  __syncthreads();
  if (t < LATD) {
    float acc = fcb[t];
#pragma unroll 8
    for (int d = 0; d < DD; ++d) acc = fmaf(fcW[t * DD + d], pb[d], acc);
    out[(size_t)g * LATD + t] = acc;
  }
}

extern "C" void kernel_launch(void* const* d_in, const int* in_sizes, int n_in,
                              void* d_out, int out_size, void* d_ws, size_t ws_size,
                              hipStream_t stream) {
  const float* x   = (const float*)d_in[0];
  const float* W1  = (const float*)d_in[1];
  const float* b1  = (const float*)d_in[2];
  const float* bng = (const float*)d_in[3];
  const float* bnb = (const float*)d_in[4];
  const float* bnm = (const float*)d_in[5];
  const float* bnv = (const float*)d_in[6];
  const float* W2  = (const float*)d_in[7];
  const float* b2  = (const float*)d_in[8];
  const float* og  = (const float*)d_in[9];
  const float* ob  = (const float*)d_in[10];
  const float* om  = (const float*)d_in[11];
  const float* ov  = (const float*)d_in[12];
  const float* fcW = (const float*)d_in[13];
  const float* fcb = (const float*)d_in[14];
  const int* ei    = (const int*)d_in[15];
  const int* batch = (const int*)d_in[16];
  const int* src  = ei;
  const int* dstp = ei + EE;

  char* ws = (char*)d_ws;
  size_t off = 0;
  auto alloc = [&](size_t bytes) {
    void* p = ws + off;
    off += (bytes + 255) & ~(size_t)255;
    return p;
  };
  unsigned short* xb0  = (unsigned short*)alloc((size_t)NN * DD * 2);
  unsigned short* xb1  = (unsigned short*)alloc((size_t)NN * DD * 2);
  char* aggsw   = (char*)alloc((size_t)NN * DD * 2);
  uint4* wb     = (uint4*)alloc((size_t)6 * 2048 * 16);
  int* row_ptr  = (int*)alloc((NN + 1) * 4);
  int* cursor   = (int*)alloc(NN * 4);
  int* counts   = (int*)alloc(NN * 4);   // 200192 padded
  int* binCnt   = (int*)alloc(256);
  int* binCursor= (int*)alloc(256);
  int* perm     = (int*)alloc(NN * 4);
  int* col      = (int*)alloc(EE * 4);
  int* bsum     = (int*)alloc(256 * 4);
  float* pooled = (float*)alloc(GG * DD * 4);

  // zero counts + binCnt in one shot (contiguous in ws)
  hipMemsetAsync(counts, 0, ((NN * 4 + 255) & ~255) + 256, stream);
  hipMemsetAsync(pooled, 0, GG * DD * 4, stream);

  prep_kernel<<<CVT_BLK + WCV_BLK + HIST_BLK, 256, 0, stream>>>(
      (const float4*)x, (uint4*)xb0, W1, W2, wb, dstp, counts);

  const int NB = (NN + 255) / 256;  // 196
  scan1_kernel<<<NB, 256, 0, stream>>>(counts, row_ptr, bsum, binCnt, NN);
  scan2_kernel<<<1, 256, 0, stream>>>(bsum, NB, binCnt, binCursor);
  scan3_kernel<<<NB, 256, 0, stream>>>(row_ptr, cursor, bsum, counts, binCursor, perm, NN);
  fill_kernel<<<(EE + 255) / 256, 256, 0, stream>>>(src, dstp, cursor, col, EE);

  unsigned short* xcur = xb0;
  unsigned short* xnext = xb1;
  const int GB = (NN + 63) / 64;    // 782
  for (int i = 0; i < LL; ++i) {
    agg_kernel<<<(NN * 16 + 255) / 256, 256, 0, stream>>>(
        (const uint4*)xcur, row_ptr, col, perm, aggsw, NN);
    if (i < LL - 1) {
      mlp64<false><<<GB, 256, 0, stream>>>(
          (const uint4*)aggsw, xnext,
          wb + (size_t)i * 4096, wb + (size_t)i * 4096 + 2048,
          b1 + i * DD, bng + i * DD, bnb + i * DD, bnm + i * DD, bnv + i * DD,
          b2 + i * DD, batch, pooled, NN);
    } else {
      mlp64<true><<<GB, 256, 0, stream>>>(
          (const uint4*)aggsw, xnext,
          wb + (size_t)i * 4096, wb + (size_t)i * 4096 + 2048,
          b1 + i * DD, bng + i * DD, bnb + i * DD, bnm + i * DD, bnv + i * DD,
          b2 + i * DD, batch, pooled, NN);
    }
    unsigned short* t = xcur; xcur = xnext; xnext = t;
  }
  head_kernel<<<GG, 128, 0, stream>>>(pooled, og, ob, om, ov, fcW, fcb, (float*)d_out);
}

// Round 6
// 337.691 us; speedup vs baseline: 1.3959x; 1.3959x over previous
//
#include <hip/hip_runtime.h>
#include <cstdint>
#include <cstddef>

#define NN 50000
#define EE 640000
#define DD 128
#define LL 3
#define GG 256
#define LATD 64

typedef __attribute__((ext_vector_type(8))) __bf16 bf16x8;
typedef __attribute__((ext_vector_type(4))) float f32x4;

__device__ __forceinline__ unsigned short f2bf(float f) {
  __bf16 h = (__bf16)f;
  return __builtin_bit_cast(unsigned short, h);
}
__device__ __forceinline__ float bf2f(unsigned int u16) {
  unsigned int x = u16 << 16;
  return __builtin_bit_cast(float, x);
}
__device__ __forceinline__ void unpack8(uint4 v, float* f) {
  f[0] = bf2f(v.x & 0xffffu); f[1] = bf2f(v.x >> 16);
  f[2] = bf2f(v.y & 0xffffu); f[3] = bf2f(v.y >> 16);
  f[4] = bf2f(v.z & 0xffffu); f[5] = bf2f(v.z >> 16);
  f[6] = bf2f(v.w & 0xffffu); f[7] = bf2f(v.w >> 16);
}
__device__ __forceinline__ void acc8(uint4 v, float* f) {
  f[0] += bf2f(v.x & 0xffffu); f[1] += bf2f(v.x >> 16);
  f[2] += bf2f(v.y & 0xffffu); f[3] += bf2f(v.y >> 16);
  f[4] += bf2f(v.z & 0xffffu); f[5] += bf2f(v.z >> 16);
  f[6] += bf2f(v.w & 0xffffu); f[7] += bf2f(v.w >> 16);
}
__device__ __forceinline__ uint4 pack8(const float* f) {
  uint4 v;
  v.x = f2bf(f[0]) | ((unsigned)f2bf(f[1]) << 16);
  v.y = f2bf(f[2]) | ((unsigned)f2bf(f[3]) << 16);
  v.z = f2bf(f[4]) | ((unsigned)f2bf(f[5]) << 16);
  v.w = f2bf(f[6]) | ((unsigned)f2bf(f[7]) << 16);
  return v;
}

#define SWZ(byte_, row_) ((byte_) ^ (((row_) & 7) << 4))

// ---------- x fp32 -> bf16 ----------
__global__ __launch_bounds__(256) void cvt_kernel(const float4* __restrict__ x,
                                                  uint4* __restrict__ xb) {
  int t = blockIdx.x * 256 + threadIdx.x;   // < 800000 exact
  float4 a = x[t * 2], b = x[t * 2 + 1];
  float f[8] = {a.x, a.y, a.z, a.w, b.x, b.y, b.z, b.w};
  xb[t] = pack8(f);
}

// ---------- weights fp32 -> bf16, pre-swizzled ----------
__global__ __launch_bounds__(256) void wcvt_kernel(const float* __restrict__ W1,
                                                   const float* __restrict__ W2,
                                                   uint4* __restrict__ wb) {
  int t = blockIdx.x * 256 + threadIdx.x;   // < 12288 exact
  int m = t >> 11;            // matrix 0..5: layer*2 + (0=W1,1=W2)
  int q = t & 2047;           // 16B chunk within matrix
  int byte = q * 16;
  int row = byte >> 8;
  int inner = byte & 255;
  int isrc = inner ^ ((row & 7) << 4);   // inverse swizzle (involution)
  int k0 = isrc >> 1;
  const float* Wsrc = (m & 1) ? W2 : W1;
  const float* p = Wsrc + ((size_t)(m >> 1) * DD * DD + row * DD + k0);
  float4 f0 = ((const float4*)p)[0], f1 = ((const float4*)p)[1];
  float f[8] = {f0.x, f0.y, f0.z, f0.w, f1.x, f1.y, f1.z, f1.w};
  wb[(size_t)m * 2048 + q] = pack8(f);
}

// ---------- CSR build ----------
__global__ __launch_bounds__(256) void hist_kernel(const int* __restrict__ dst,
                                                   int* __restrict__ counts, int E) {
  int e = blockIdx.x * blockDim.x + threadIdx.x;
  if (e < E) atomicAdd(&counts[dst[e]], 1);
}

__global__ __launch_bounds__(256) void scan1_kernel(const int* __restrict__ counts,
                                                    int* __restrict__ rp,
                                                    int* __restrict__ bsum, int n) {
  int i = blockIdx.x * 256 + threadIdx.x;
  int v = (i < n) ? counts[i] : 0;
  int lane = threadIdx.x & 63, w = threadIdx.x >> 6;
  int s = v;
#pragma unroll
  for (int off = 1; off < 64; off <<= 1) {
    int u = __shfl_up(s, off);
    if (lane >= off) s += u;
  }
  __shared__ int ws[4];
  if (lane == 63) ws[w] = s;
  __syncthreads();
  int add = 0;
#pragma unroll
  for (int k = 0; k < 4; ++k) if (k < w) add += ws[k];
  int incl = s + add;
  if (i < n) rp[i] = incl - v;
  if (threadIdx.x == 255) bsum[blockIdx.x] = incl;
}

__global__ __launch_bounds__(256) void scan2_kernel(int* __restrict__ bsum, int nb) {
  int t = threadIdx.x;
  int v = (t < nb) ? bsum[t] : 0;
  int lane = t & 63, w = t >> 6;
  int s = v;
#pragma unroll
  for (int off = 1; off < 64; off <<= 1) {
    int u = __shfl_up(s, off);
    if (lane >= off) s += u;
  }
  __shared__ int ws[4];
  if (lane == 63) ws[w] = s;
  __syncthreads();
  int add = 0;
#pragma unroll
  for (int k = 0; k < 4; ++k) if (k < w) add += ws[k];
  int incl = s + add;
  if (t < nb) bsum[t] = incl - v;
}

__global__ __launch_bounds__(256) void scan3_kernel(int* __restrict__ rp,
                                                    int* __restrict__ cursor,
                                                    const int* __restrict__ bsum, int n) {
  int i = blockIdx.x * 256 + threadIdx.x;
  if (i < n) {
    int v = rp[i] + bsum[blockIdx.x];
    rp[i] = v;
    cursor[i] = v;
  }
  if (i == 0) rp[n] = EE;
}

__global__ __launch_bounds__(256) void fill_kernel(const int* __restrict__ src,
                                                   const int* __restrict__ dst,
                                                   int* __restrict__ cursor,
                                                   int* __restrict__ col, int E) {
  int e = blockIdx.x * blockDim.x + threadIdx.x;
  if (e < E) {
    int p = atomicAdd(&cursor[dst[e]], 1);
    col[p] = src[e];
  }
}

// ---------- GIN aggregation: 8-deep ILP gather, pre-swizzled output ----------
__global__ __launch_bounds__(256, 8) void agg_kernel(const uint4* __restrict__ xin,
                                                     const int* __restrict__ row_ptr,
                                                     const int* __restrict__ colv,
                                                     char* __restrict__ aggsw, int n) {
  int tid = blockIdx.x * 256 + threadIdx.x;
  int node = tid >> 4;
  int c = tid & 15;
  if (node >= n) return;
  float acc[8];
  unpack8(xin[(size_t)node * 16 + c], acc);
  int s = row_ptr[node], e = row_ptr[node + 1];
  int j = s;
  for (; j + 8 <= e; j += 8) {
    int i0 = colv[j],     i1 = colv[j + 1], i2 = colv[j + 2], i3 = colv[j + 3];
    int i4 = colv[j + 4], i5 = colv[j + 5], i6 = colv[j + 6], i7 = colv[j + 7];
    uint4 v0 = xin[(size_t)i0 * 16 + c];
    uint4 v1 = xin[(size_t)i1 * 16 + c];
    uint4 v2 = xin[(size_t)i2 * 16 + c];
    uint4 v3 = xin[(size_t)i3 * 16 + c];
    uint4 v4 = xin[(size_t)i4 * 16 + c];
    uint4 v5 = xin[(size_t)i5 * 16 + c];
    uint4 v6 = xin[(size_t)i6 * 16 + c];
    uint4 v7 = xin[(size_t)i7 * 16 + c];
    acc8(v0, acc); acc8(v1, acc); acc8(v2, acc); acc8(v3, acc);
    acc8(v4, acc); acc8(v5, acc); acc8(v6, acc); acc8(v7, acc);
  }
  for (; j + 2 <= e; j += 2) {
    uint4 v0 = xin[(size_t)colv[j] * 16 + c];
    uint4 v1 = xin[(size_t)colv[j + 1] * 16 + c];
    acc8(v0, acc); acc8(v1, acc);
  }
  if (j < e) acc8(xin[(size_t)colv[j] * 16 + c], acc);
  // write pre-swizzled so mlp64 staging is a pure linear copy
  unsigned byte = (unsigned)node * 256 + ((c * 16) ^ ((node & 7) << 4));
  *(uint4*)(aggsw + byte) = pack8(acc);
}

// ---------- MFMA MLP: 64-row tile, 80KB LDS; optional fused pooling ----------
template <bool POOL>
__global__ __launch_bounds__(256) void mlp64(
    const uint4* __restrict__ aggsw, unsigned short* __restrict__ xout,
    const uint4* __restrict__ w1b, const uint4* __restrict__ w2b,
    const float* __restrict__ b1, const float* __restrict__ bng,
    const float* __restrict__ bnb, const float* __restrict__ bnm,
    const float* __restrict__ bnv, const float* __restrict__ b2,
    const int* __restrict__ batch, float* __restrict__ pooled, int n) {
  __shared__ __align__(16) char smem[81920];
  char* w1p = smem;           // 32KB bf16 W1, pre-swizzled (reused as pool partials)
  char* w2p = smem + 32768;   // 32KB bf16 W2
  char* xp  = smem + 65536;   // 16KB: 64 rows x 256B, pre-swizzled in global

#pragma unroll
  for (int it = 0; it < 8; ++it) {
    int q = it * 256 + threadIdx.x;
    ((uint4*)w1p)[q] = w1b[q];
    ((uint4*)w2p)[q] = w2b[q];
  }
  int base = blockIdx.x * 64;
#pragma unroll
  for (int it = 0; it < 4; ++it) {
    int q = it * 256 + threadIdx.x;   // 1024 chunks of 16B, linear (pre-swizzled)
    int grow = base + (q >> 4);
    uint4 v = make_uint4(0, 0, 0, 0);
    if (grow < n) v = aggsw[(size_t)base * 16 + q];
    ((uint4*)xp)[q] = v;
  }
  __syncthreads();

  int lane = threadIdx.x & 63;
  int c = lane & 15;
  int kq = lane >> 4;
  int wave = threadIdx.x >> 6;
  int r0 = wave * 16;

  float b1v[8], sv[8], tv[8], b2v[8];
#pragma unroll
  for (int ni = 0; ni < 8; ++ni) {
    int cc = ni * 16 + c;
    b1v[ni] = b1[cc];
    float s = bng[cc] * rsqrtf(bnv[cc] + 1e-5f);
    sv[ni] = s;
    tv[ni] = bnb[cc] - bnm[cc] * s;
    b2v[ni] = b2[cc];
  }

  f32x4 acc[8];
#pragma unroll
  for (int ni = 0; ni < 8; ++ni) acc[ni] = (f32x4){0.f, 0.f, 0.f, 0.f};

  // GEMM1: h = X @ W1^T
#pragma unroll
  for (int ks = 0; ks < 4; ++ks) {
    int row = r0 + c;
    bf16x8 a = *(const bf16x8*)(xp + SWZ(row * 256 + ks * 64 + kq * 16, row));
#pragma unroll
    for (int ni = 0; ni < 8; ++ni) {
      int wr = ni * 16 + c;
      bf16x8 bfr = *(const bf16x8*)(w1p + SWZ(wr * 256 + ks * 64 + kq * 16, wr));
      acc[ni] = __builtin_amdgcn_mfma_f32_16x16x32_bf16(a, bfr, acc[ni], 0, 0, 0);
    }
  }

  // epilogue 1: leaky + BN -> back to X LDS (wave-local rows)
#pragma unroll
  for (int ni = 0; ni < 8; ++ni)
#pragma unroll
    for (int r = 0; r < 4; ++r) {
      float h = acc[ni][r] + b1v[ni];
      h = h >= 0.f ? h : 0.2f * h;
      h = h * sv[ni] + tv[ni];
      int row = r0 + kq * 4 + r;
      *(__bf16*)(xp + SWZ(row * 256 + (ni * 16 + c) * 2, row)) = (__bf16)h;
    }
  __syncthreads();   // all GEMM1 w1p reads + epi1 xp writes complete

  if (POOL) {
    float* part = (float*)w1p;   // 8 slots x 128 dims
#pragma unroll
    for (int k = 0; k < 4; ++k) part[k * 256 + threadIdx.x] = 0.f;
    __syncthreads();
  }

#pragma unroll
  for (int ni = 0; ni < 8; ++ni) acc[ni] = (f32x4){0.f, 0.f, 0.f, 0.f};

  // GEMM2: x = h @ W2^T
#pragma unroll
  for (int ks = 0; ks < 4; ++ks) {
    int row = r0 + c;
    bf16x8 a = *(const bf16x8*)(xp + SWZ(row * 256 + ks * 64 + kq * 16, row));
#pragma unroll
    for (int ni = 0; ni < 8; ++ni) {
      int wr = ni * 16 + c;
      bf16x8 bfr = *(const bf16x8*)(w2p + SWZ(wr * 256 + ks * 64 + kq * 16, wr));
      acc[ni] = __builtin_amdgcn_mfma_f32_16x16x32_bf16(a, bfr, acc[ni], 0, 0, 0);
    }
  }

  // epilogue 2
  if (POOL) {
    int gb = batch[base];
    float* part = (float*)w1p;
#pragma unroll
    for (int r = 0; r < 4; ++r) {
      int grow = base + r0 + kq * 4 + r;
      if (grow < n) {
        int slot = batch[grow] - gb;
#pragma unroll
        for (int ni = 0; ni < 8; ++ni) {
          float xo = acc[ni][r] + b2v[ni];
          xo = xo >= 0.f ? xo : 0.2f * xo;
          if (slot < 8) atomicAdd(&part[slot * DD + ni * 16 + c], xo);
          else atomicAdd(&pooled[(size_t)(gb + slot) * DD + ni * 16 + c], xo);
        }
      }
    }
    __syncthreads();
#pragma unroll
    for (int k = 0; k < 4; ++k) {
      int idx = k * 256 + threadIdx.x;      // 0..1023 = slot*128 + dim
      float v = part[idx];
      if (v != 0.f)
        atomicAdd(&pooled[(size_t)(gb + (idx >> 7)) * DD + (idx & 127)], v);
    }
  } else {
#pragma unroll
    for (int ni = 0; ni < 8; ++ni)
#pragma unroll
      for (int r = 0; r < 4; ++r) {
        float xo = acc[ni][r] + b2v[ni];
        xo = xo >= 0.f ? xo : 0.2f * xo;
        int grow = base + r0 + kq * 4 + r;
        if (grow < n) xout[(size_t)grow * DD + ni * 16 + c] = f2bf(xo);
      }
  }
}

// ---------- head ----------
__global__ __launch_bounds__(128) void head_kernel(const float* __restrict__ pooled,
    const float* __restrict__ og, const float* __restrict__ ob,
    const float* __restrict__ om, const float* __restrict__ ov,
    const float* __restrict__ fcW, const float* __restrict__ fcb,
    float* __restrict__ out) {
  __shared__ float pb[DD];
  int g = blockIdx.x;
  int t = threadIdx.x;
  float s = og[t] * rsqrtf(ov[t] + 1e-5f);
  pb[t] = (pooled[(size_t)g * DD + t] - om[t]) * s + ob[t];
  __syncthreads();
  if (t < LATD) {
    float acc = fcb[t];
#pragma unroll 8
    for (int d = 0; d < DD; ++d) acc = fmaf(fcW[t * DD + d], pb[d], acc);
    out[(size_t)g * LATD + t] = acc;
  }
}

extern "C" void kernel_launch(void* const* d_in, const int* in_sizes, int n_in,
                              void* d_out, int out_size, void* d_ws, size_t ws_size,
                              hipStream_t stream) {
  const float* x   = (const float*)d_in[0];
  const float* W1  = (const float*)d_in[1];
  const float* b1  = (const float*)d_in[2];
  const float* bng = (const float*)d_in[3];
  const float* bnb = (const float*)d_in[4];
  const float* bnm = (const float*)d_in[5];
  const float* bnv = (const float*)d_in[6];
  const float* W2  = (const float*)d_in[7];
  const float* b2  = (const float*)d_in[8];
  const float* og  = (const float*)d_in[9];
  const float* ob  = (const float*)d_in[10];
  const float* om  = (const float*)d_in[11];
  const float* ov  = (const float*)d_in[12];
  const float* fcW = (const float*)d_in[13];
  const float* fcb = (const float*)d_in[14];
  const int* ei    = (const int*)d_in[15];
  const int* batch = (const int*)d_in[16];
  const int* src  = ei;
  const int* dstp = ei + EE;

  char* ws = (char*)d_ws;
  size_t off = 0;
  auto alloc = [&](size_t bytes) {
    void* p = ws + off;
    off += (bytes + 255) & ~(size_t)255;
    return p;
  };
  unsigned short* xb0  = (unsigned short*)alloc((size_t)NN * DD * 2);
  unsigned short* xb1  = (unsigned short*)alloc((size_t)NN * DD * 2);
  char* aggsw   = (char*)alloc((size_t)NN * DD * 2);
  uint4* wb     = (uint4*)alloc((size_t)6 * 2048 * 16);
  int* row_ptr  = (int*)alloc((NN + 1) * 4);
  int* cursor   = (int*)alloc(NN * 4);
  int* counts   = (int*)alloc(NN * 4);
  int* col      = (int*)alloc(EE * 4);
  int* bsum     = (int*)alloc(256 * 4);
  float* pooled = (float*)alloc(GG * DD * 4);

  hipMemsetAsync(counts, 0, NN * 4, stream);
  hipMemsetAsync(pooled, 0, GG * DD * 4, stream);

  cvt_kernel<<<3125, 256, 0, stream>>>((const float4*)x, (uint4*)xb0);
  wcvt_kernel<<<48, 256, 0, stream>>>(W1, W2, wb);

  const int NB = (NN + 255) / 256;  // 196
  hist_kernel<<<(EE + 255) / 256, 256, 0, stream>>>(dstp, counts, EE);
  scan1_kernel<<<NB, 256, 0, stream>>>(counts, row_ptr, bsum, NN);
  scan2_kernel<<<1, 256, 0, stream>>>(bsum, NB);
  scan3_kernel<<<NB, 256, 0, stream>>>(row_ptr, cursor, bsum, NN);
  fill_kernel<<<(EE + 255) / 256, 256, 0, stream>>>(src, dstp, cursor, col, EE);

  unsigned short* xcur = xb0;
  unsigned short* xnext = xb1;
  const int GB = (NN + 63) / 64;    // 782
  for (int i = 0; i < LL; ++i) {
    agg_kernel<<<(NN * 16 + 255) / 256, 256, 0, stream>>>(
        (const uint4*)xcur, row_ptr, col, aggsw, NN);
    if (i < LL - 1) {
      mlp64<false><<<GB, 256, 0, stream>>>(
          (const uint4*)aggsw, xnext,
          wb + (size_t)i * 4096, wb + (size_t)i * 4096 + 2048,
          b1 + i * DD, bng + i * DD, bnb + i * DD, bnm + i * DD, bnv + i * DD,
          b2 + i * DD, batch, pooled, NN);
    } else {
      mlp64<true><<<GB, 256, 0, stream>>>(
          (const uint4*)aggsw, xnext,
          wb + (size_t)i * 4096, wb + (size_t)i * 4096 + 2048,
          b1 + i * DD, bng + i * DD, bnb + i * DD, bnm + i * DD, bnv + i * DD,
          b2 + i * DD, batch, pooled, NN);
    }
    unsigned short* t = xcur; xcur = xnext; xnext = t;
  }
  head_kernel<<<GG, 128, 0, stream>>>(pooled, og, ob, om, ov, fcW, fcb, (float*)d_out);
}

// Round 7
// 246.143 us; speedup vs baseline: 1.9151x; 1.3719x over previous
//
#include <hip/hip_runtime.h>
#include <cstdint>
#include <cstddef>

#define NN 50000
#define EE 640000
#define DD 128
#define LL 3
#define GG 256
#define LATD 64

typedef __attribute__((ext_vector_type(8))) __bf16 bf16x8;
typedef __attribute__((ext_vector_type(4))) float f32x4;

__device__ __forceinline__ unsigned short f2bf(float f) {
  __bf16 h = (__bf16)f;
  return __builtin_bit_cast(unsigned short, h);
}
__device__ __forceinline__ float bf2f(unsigned int u16) {
  unsigned int x = u16 << 16;
  return __builtin_bit_cast(float, x);
}
__device__ __forceinline__ void unpack8(uint4 v, float* f) {
  f[0] = bf2f(v.x & 0xffffu); f[1] = bf2f(v.x >> 16);
  f[2] = bf2f(v.y & 0xffffu); f[3] = bf2f(v.y >> 16);
  f[4] = bf2f(v.z & 0xffffu); f[5] = bf2f(v.z >> 16);
  f[6] = bf2f(v.w & 0xffffu); f[7] = bf2f(v.w >> 16);
}
__device__ __forceinline__ void acc8(uint4 v, float* f) {
  f[0] += bf2f(v.x & 0xffffu); f[1] += bf2f(v.x >> 16);
  f[2] += bf2f(v.y & 0xffffu); f[3] += bf2f(v.y >> 16);
  f[4] += bf2f(v.z & 0xffffu); f[5] += bf2f(v.z >> 16);
  f[6] += bf2f(v.w & 0xffffu); f[7] += bf2f(v.w >> 16);
}
__device__ __forceinline__ uint4 pack8(const float* f) {
  uint4 v;
  v.x = f2bf(f[0]) | ((unsigned)f2bf(f[1]) << 16);
  v.y = f2bf(f[2]) | ((unsigned)f2bf(f[3]) << 16);
  v.z = f2bf(f[4]) | ((unsigned)f2bf(f[5]) << 16);
  v.w = f2bf(f[6]) | ((unsigned)f2bf(f[7]) << 16);
  return v;
}

#define SWZ(byte_, row_) ((byte_) ^ (((row_) & 7) << 4))

// ---------- x fp32 -> bf16 ----------
__global__ __launch_bounds__(256) void cvt_kernel(const float4* __restrict__ x,
                                                  uint4* __restrict__ xb) {
  int t = blockIdx.x * 256 + threadIdx.x;   // < 800000 exact
  float4 a = x[t * 2], b = x[t * 2 + 1];
  float f[8] = {a.x, a.y, a.z, a.w, b.x, b.y, b.z, b.w};
  xb[t] = pack8(f);
}

// ---------- weights fp32 -> bf16, pre-swizzled ----------
__global__ __launch_bounds__(256) void wcvt_kernel(const float* __restrict__ W1,
                                                   const float* __restrict__ W2,
                                                   uint4* __restrict__ wb) {
  int t = blockIdx.x * 256 + threadIdx.x;   // < 12288 exact
  int m = t >> 11;            // matrix 0..5: layer*2 + (0=W1,1=W2)
  int q = t & 2047;           // 16B chunk within matrix
  int byte = q * 16;
  int row = byte >> 8;
  int inner = byte & 255;
  int isrc = inner ^ ((row & 7) << 4);   // inverse swizzle (involution)
  int k0 = isrc >> 1;
  const float* Wsrc = (m & 1) ? W2 : W1;
  const float* p = Wsrc + ((size_t)(m >> 1) * DD * DD + row * DD + k0);
  float4 f0 = ((const float4*)p)[0], f1 = ((const float4*)p)[1];
  float f[8] = {f0.x, f0.y, f0.z, f0.w, f1.x, f1.y, f1.z, f1.w};
  wb[(size_t)m * 2048 + q] = pack8(f);
}

// ---------- CSR build ----------
__global__ __launch_bounds__(256) void hist_kernel(const int* __restrict__ dst,
                                                   int* __restrict__ counts, int E) {
  int e = blockIdx.x * blockDim.x + threadIdx.x;
  if (e < E) atomicAdd(&counts[dst[e]], 1);
}

__global__ __launch_bounds__(256) void scan1_kernel(const int* __restrict__ counts,
                                                    int* __restrict__ rp,
                                                    int* __restrict__ bsum, int n) {
  int i = blockIdx.x * 256 + threadIdx.x;
  int v = (i < n) ? counts[i] : 0;
  int lane = threadIdx.x & 63, w = threadIdx.x >> 6;
  int s = v;
#pragma unroll
  for (int off = 1; off < 64; off <<= 1) {
    int u = __shfl_up(s, off);
    if (lane >= off) s += u;
  }
  __shared__ int ws[4];
  if (lane == 63) ws[w] = s;
  __syncthreads();
  int add = 0;
#pragma unroll
  for (int k = 0; k < 4; ++k) if (k < w) add += ws[k];
  int incl = s + add;
  if (i < n) rp[i] = incl - v;
  if (threadIdx.x == 255) bsum[blockIdx.x] = incl;
}

__global__ __launch_bounds__(256) void scan2_kernel(int* __restrict__ bsum, int nb) {
  int t = threadIdx.x;
  int v = (t < nb) ? bsum[t] : 0;
  int lane = t & 63, w = t >> 6;
  int s = v;
#pragma unroll
  for (int off = 1; off < 64; off <<= 1) {
    int u = __shfl_up(s, off);
    if (lane >= off) s += u;
  }
  __shared__ int ws[4];
  if (lane == 63) ws[w] = s;
  __syncthreads();
  int add = 0;
#pragma unroll
  for (int k = 0; k < 4; ++k) if (k < w) add += ws[k];
  int incl = s + add;
  if (t < nb) bsum[t] = incl - v;
}

__global__ __launch_bounds__(256) void scan3_kernel(int* __restrict__ rp,
                                                    int* __restrict__ cursor,
                                                    const int* __restrict__ bsum, int n) {
  int i = blockIdx.x * 256 + threadIdx.x;
  if (i < n) {
    int v = rp[i] + bsum[blockIdx.x];
    rp[i] = v;
    cursor[i] = v;
  }
  if (i == 0) rp[n] = EE;
}

__global__ __launch_bounds__(256) void fill_kernel(const int* __restrict__ src,
                                                   const int* __restrict__ dst,
                                                   int* __restrict__ cursor,
                                                   int* __restrict__ col, int E) {
  int e = blockIdx.x * blockDim.x + threadIdx.x;
  if (e < E) {
    int p = atomicAdd(&cursor[dst[e]], 1);
    col[p] = src[e];
  }
}

// ---------- GIN aggregation: 8-deep ILP gather, NO spill (min-waves=4 -> 128 VGPR cap) ----------
__global__ __launch_bounds__(256, 4) void agg_kernel(const uint4* __restrict__ xin,
                                                     const int* __restrict__ row_ptr,
                                                     const int* __restrict__ colv,
                                                     uint4* __restrict__ agg, int n) {
  int tid = blockIdx.x * 256 + threadIdx.x;
  int node = tid >> 4;
  int c = tid & 15;
  if (node >= n) return;
  float acc[8];
  unpack8(xin[(size_t)node * 16 + c], acc);
  int s = row_ptr[node], e = row_ptr[node + 1];
  int j = s;
  for (; j + 8 <= e; j += 8) {
    int i0 = colv[j],     i1 = colv[j + 1], i2 = colv[j + 2], i3 = colv[j + 3];
    int i4 = colv[j + 4], i5 = colv[j + 5], i6 = colv[j + 6], i7 = colv[j + 7];
    uint4 v0 = xin[(size_t)i0 * 16 + c];
    uint4 v1 = xin[(size_t)i1 * 16 + c];
    uint4 v2 = xin[(size_t)i2 * 16 + c];
    uint4 v3 = xin[(size_t)i3 * 16 + c];
    uint4 v4 = xin[(size_t)i4 * 16 + c];
    uint4 v5 = xin[(size_t)i5 * 16 + c];
    uint4 v6 = xin[(size_t)i6 * 16 + c];
    uint4 v7 = xin[(size_t)i7 * 16 + c];
    acc8(v0, acc); acc8(v1, acc); acc8(v2, acc); acc8(v3, acc);
    acc8(v4, acc); acc8(v5, acc); acc8(v6, acc); acc8(v7, acc);
  }
  for (; j + 2 <= e; j += 2) {
    uint4 v0 = xin[(size_t)colv[j] * 16 + c];
    uint4 v1 = xin[(size_t)colv[j + 1] * 16 + c];
    acc8(v0, acc); acc8(v1, acc);
  }
  if (j < e) acc8(xin[(size_t)colv[j] * 16 + c], acc);
  agg[(size_t)node * 16 + c] = pack8(acc);
}

// ---------- MFMA MLP: 64-row tile, 80KB LDS, 256 threads (round-4 proven) ----------
__global__ __launch_bounds__(256) void mlp64(
    const uint4* __restrict__ aggb, unsigned short* __restrict__ xout,
    const uint4* __restrict__ w1b, const uint4* __restrict__ w2b,
    const float* __restrict__ b1, const float* __restrict__ bng,
    const float* __restrict__ bnb, const float* __restrict__ bnm,
    const float* __restrict__ bnv, const float* __restrict__ b2, int n) {
  __shared__ __align__(16) char smem[81920];
  char* w1p = smem;           // 32KB bf16 W1, pre-swizzled
  char* w2p = smem + 32768;   // 32KB bf16 W2
  char* xp  = smem + 65536;   // 16KB: 64 rows x 256B, swizzled

#pragma unroll
  for (int it = 0; it < 8; ++it) {
    int q = it * 256 + threadIdx.x;
    ((uint4*)w1p)[q] = w1b[q];
    ((uint4*)w2p)[q] = w2b[q];
  }
  int base = blockIdx.x * 64;
#pragma unroll
  for (int it = 0; it < 4; ++it) {
    int t = it * 256 + threadIdx.x;
    int row = t >> 4, c = t & 15;
    int grow = base + row;
    uint4 v = make_uint4(0, 0, 0, 0);
    if (grow < n) v = aggb[(size_t)grow * 16 + c];
    *(uint4*)(xp + SWZ(row * 256 + c * 16, row)) = v;
  }
  __syncthreads();

  int lane = threadIdx.x & 63;
  int c = lane & 15;
  int kq = lane >> 4;
  int wave = threadIdx.x >> 6;
  int r0 = wave * 16;

  float b1v[8], sv[8], tv[8], b2v[8];
#pragma unroll
  for (int ni = 0; ni < 8; ++ni) {
    int cc = ni * 16 + c;
    b1v[ni] = b1[cc];
    float s = bng[cc] * rsqrtf(bnv[cc] + 1e-5f);
    sv[ni] = s;
    tv[ni] = bnb[cc] - bnm[cc] * s;
    b2v[ni] = b2[cc];
  }

  f32x4 acc[8];
#pragma unroll
  for (int ni = 0; ni < 8; ++ni) acc[ni] = (f32x4){0.f, 0.f, 0.f, 0.f};

  // GEMM1: h = X @ W1^T
#pragma unroll
  for (int ks = 0; ks < 4; ++ks) {
    int row = r0 + c;
    bf16x8 a = *(const bf16x8*)(xp + SWZ(row * 256 + ks * 64 + kq * 16, row));
#pragma unroll
    for (int ni = 0; ni < 8; ++ni) {
      int wr = ni * 16 + c;
      bf16x8 bfr = *(const bf16x8*)(w1p + SWZ(wr * 256 + ks * 64 + kq * 16, wr));
      acc[ni] = __builtin_amdgcn_mfma_f32_16x16x32_bf16(a, bfr, acc[ni], 0, 0, 0);
    }
  }

  // epilogue 1: leaky + BN -> back to X LDS (wave-local rows)
#pragma unroll
  for (int ni = 0; ni < 8; ++ni)
#pragma unroll
    for (int r = 0; r < 4; ++r) {
      float h = acc[ni][r] + b1v[ni];
      h = h >= 0.f ? h : 0.2f * h;
      h = h * sv[ni] + tv[ni];
      int row = r0 + kq * 4 + r;
      *(__bf16*)(xp + SWZ(row * 256 + (ni * 16 + c) * 2, row)) = (__bf16)h;
    }
  __syncthreads();

#pragma unroll
  for (int ni = 0; ni < 8; ++ni) acc[ni] = (f32x4){0.f, 0.f, 0.f, 0.f};

  // GEMM2: x = h @ W2^T
#pragma unroll
  for (int ks = 0; ks < 4; ++ks) {
    int row = r0 + c;
    bf16x8 a = *(const bf16x8*)(xp + SWZ(row * 256 + ks * 64 + kq * 16, row));
#pragma unroll
    for (int ni = 0; ni < 8; ++ni) {
      int wr = ni * 16 + c;
      bf16x8 bfr = *(const bf16x8*)(w2p + SWZ(wr * 256 + ks * 64 + kq * 16, wr));
      acc[ni] = __builtin_amdgcn_mfma_f32_16x16x32_bf16(a, bfr, acc[ni], 0, 0, 0);
    }
  }

  // epilogue 2: leaky -> global bf16
#pragma unroll
  for (int ni = 0; ni < 8; ++ni)
#pragma unroll
    for (int r = 0; r < 4; ++r) {
      float xo = acc[ni][r] + b2v[ni];
      xo = xo >= 0.f ? xo : 0.2f * xo;
      int grow = base + r0 + kq * 4 + r;
      if (grow < n) xout[(size_t)grow * DD + ni * 16 + c] = f2bf(xo);
    }
}

// ---------- pooling: sorted batch -> run-accumulate, flush on graph change ----------
__global__ __launch_bounds__(256) void pool_kernel(const uint4* __restrict__ x,
                                                   const int* __restrict__ batch,
                                                   float* __restrict__ pooled, int n) {
  int gid = blockIdx.x * 256 + threadIdx.x;
  int grp = gid >> 4, c = gid & 15;
  int n0 = grp * 16;
  if (n0 >= n) return;
  float acc[8] = {0.f, 0.f, 0.f, 0.f, 0.f, 0.f, 0.f, 0.f};
  int curg = batch[n0];
  int end = n0 + 16 < n ? n0 + 16 : n;
  for (int node = n0; node < end; ++node) {
    int g = batch[node];
    if (g != curg) {
      float* p = pooled + (size_t)curg * DD + c * 8;
#pragma unroll
      for (int i = 0; i < 8; ++i) { atomicAdd(p + i, acc[i]); acc[i] = 0.f; }
      curg = g;
    }
    float tmp[8];
    unpack8(x[(size_t)node * 16 + c], tmp);
#pragma unroll
    for (int i = 0; i < 8; ++i) acc[i] += tmp[i];
  }
  float* p = pooled + (size_t)curg * DD + c * 8;
#pragma unroll
  for (int i = 0; i < 8; ++i) atomicAdd(p + i, acc[i]);
}

// ---------- head ----------
__global__ __launch_bounds__(128) void head_kernel(const float* __restrict__ pooled,
    const float* __restrict__ og, const float* __restrict__ ob,
    const float* __restrict__ om, const float* __restrict__ ov,
    const float* __restrict__ fcW, const float* __restrict__ fcb,
    float* __restrict__ out) {
  __shared__ float pb[DD];
  int g = blockIdx.x;
  int t = threadIdx.x;
  float s = og[t] * rsqrtf(ov[t] + 1e-5f);
  pb[t] = (pooled[(size_t)g * DD + t] - om[t]) * s + ob[t];
  __syncthreads();
  if (t < LATD) {
    float acc = fcb[t];
#pragma unroll 8
    for (int d = 0; d < DD; ++d) acc = fmaf(fcW[t * DD + d], pb[d], acc);
    out[(size_t)g * LATD + t] = acc;
  }
}

extern "C" void kernel_launch(void* const* d_in, const int* in_sizes, int n_in,
                              void* d_out, int out_size, void* d_ws, size_t ws_size,
                              hipStream_t stream) {
  const float* x   = (const float*)d_in[0];
  const float* W1  = (const float*)d_in[1];
  const float* b1  = (const float*)d_in[2];
  const float* bng = (const float*)d_in[3];
  const float* bnb = (const float*)d_in[4];
  const float* bnm = (const float*)d_in[5];
  const float* bnv = (const float*)d_in[6];
  const float* W2  = (const float*)d_in[7];
  const float* b2  = (const float*)d_in[8];
  const float* og  = (const float*)d_in[9];
  const float* ob  = (const float*)d_in[10];
  const float* om  = (const float*)d_in[11];
  const float* ov  = (const float*)d_in[12];
  const float* fcW = (const float*)d_in[13];
  const float* fcb = (const float*)d_in[14];
  const int* ei    = (const int*)d_in[15];
  const int* batch = (const int*)d_in[16];
  const int* src  = ei;
  const int* dstp = ei + EE;

  char* ws = (char*)d_ws;
  size_t off = 0;
  auto alloc = [&](size_t bytes) {
    void* p = ws + off;
    off += (bytes + 255) & ~(size_t)255;
    return p;
  };
  unsigned short* xb0  = (unsigned short*)alloc((size_t)NN * DD * 2);
  unsigned short* xb1  = (unsigned short*)alloc((size_t)NN * DD * 2);
  unsigned short* aggb = (unsigned short*)alloc((size_t)NN * DD * 2);
  uint4* wb     = (uint4*)alloc((size_t)6 * 2048 * 16);
  int* row_ptr  = (int*)alloc((NN + 1) * 4);
  int* cursor   = (int*)alloc(NN * 4);
  int* counts   = (int*)alloc(NN * 4);
  int* col      = (int*)alloc(EE * 4);
  int* bsum     = (int*)alloc(256 * 4);
  float* pooled = (float*)alloc(GG * DD * 4);

  hipMemsetAsync(counts, 0, NN * 4, stream);
  hipMemsetAsync(pooled, 0, GG * DD * 4, stream);

  cvt_kernel<<<3125, 256, 0, stream>>>((const float4*)x, (uint4*)xb0);
  wcvt_kernel<<<48, 256, 0, stream>>>(W1, W2, wb);

  const int NB = (NN + 255) / 256;  // 196
  hist_kernel<<<(EE + 255) / 256, 256, 0, stream>>>(dstp, counts, EE);
  scan1_kernel<<<NB, 256, 0, stream>>>(counts, row_ptr, bsum, NN);
  scan2_kernel<<<1, 256, 0, stream>>>(bsum, NB);
  scan3_kernel<<<NB, 256, 0, stream>>>(row_ptr, cursor, bsum, NN);
  fill_kernel<<<(EE + 255) / 256, 256, 0, stream>>>(src, dstp, cursor, col, EE);

  unsigned short* xcur = xb0;
  unsigned short* xnext = xb1;
  const int GB = (NN + 63) / 64;    // 782
  for (int i = 0; i < LL; ++i) {
    agg_kernel<<<(NN * 16 + 255) / 256, 256, 0, stream>>>(
        (const uint4*)xcur, row_ptr, col, (uint4*)aggb, NN);
    mlp64<<<GB, 256, 0, stream>>>(
        (const uint4*)aggb, xnext,
        wb + (size_t)i * 4096, wb + (size_t)i * 4096 + 2048,
        b1 + i * DD, bng + i * DD, bnb + i * DD, bnm + i * DD, bnv + i * DD,
        b2 + i * DD, NN);
    unsigned short* t = xcur; xcur = xnext; xnext = t;
  }
  pool_kernel<<<(NN * 16 + 255) / 256, 256, 0, stream>>>(
      (const uint4*)xcur, batch, pooled, NN);
  head_kernel<<<GG, 128, 0, stream>>>(pooled, og, ob, om, ov, fcW, fcb, (float*)d_out);
}

// Round 8
// 240.602 us; speedup vs baseline: 1.9592x; 1.0230x over previous
//
#include <hip/hip_runtime.h>
#include <cstdint>
#include <cstddef>

#define NN 50000
#define EE 640000
#define DD 128
#define LL 3
#define GG 256
#define LATD 64

typedef __attribute__((ext_vector_type(8))) __bf16 bf16x8;
typedef __attribute__((ext_vector_type(4))) float f32x4;

__device__ __forceinline__ unsigned short f2bf(float f) {
  __bf16 h = (__bf16)f;
  return __builtin_bit_cast(unsigned short, h);
}
__device__ __forceinline__ float bf2f(unsigned int u16) {
  unsigned int x = u16 << 16;
  return __builtin_bit_cast(float, x);
}
__device__ __forceinline__ void unpack8(uint4 v, float* f) {
  f[0] = bf2f(v.x & 0xffffu); f[1] = bf2f(v.x >> 16);
  f[2] = bf2f(v.y & 0xffffu); f[3] = bf2f(v.y >> 16);
  f[4] = bf2f(v.z & 0xffffu); f[5] = bf2f(v.z >> 16);
  f[6] = bf2f(v.w & 0xffffu); f[7] = bf2f(v.w >> 16);
}
__device__ __forceinline__ void acc8(uint4 v, float* f) {
  f[0] += bf2f(v.x & 0xffffu); f[1] += bf2f(v.x >> 16);
  f[2] += bf2f(v.y & 0xffffu); f[3] += bf2f(v.y >> 16);
  f[4] += bf2f(v.z & 0xffffu); f[5] += bf2f(v.z >> 16);
  f[6] += bf2f(v.w & 0xffffu); f[7] += bf2f(v.w >> 16);
}
__device__ __forceinline__ uint4 pack8(const float* f) {
  uint4 v;
  v.x = f2bf(f[0]) | ((unsigned)f2bf(f[1]) << 16);
  v.y = f2bf(f[2]) | ((unsigned)f2bf(f[3]) << 16);
  v.z = f2bf(f[4]) | ((unsigned)f2bf(f[5]) << 16);
  v.w = f2bf(f[6]) | ((unsigned)f2bf(f[7]) << 16);
  return v;
}

#define SWZ(byte_, row_) ((byte_) ^ (((row_) & 7) << 4))

// ---------- x fp32 -> bf16 ----------
__global__ __launch_bounds__(256) void cvt_kernel(const float4* __restrict__ x,
                                                  uint4* __restrict__ xb) {
  int t = blockIdx.x * 256 + threadIdx.x;   // < 800000 exact
  float4 a = x[t * 2], b = x[t * 2 + 1];
  float f[8] = {a.x, a.y, a.z, a.w, b.x, b.y, b.z, b.w};
  xb[t] = pack8(f);
}

// ---------- weights fp32 -> bf16, pre-swizzled ----------
__global__ __launch_bounds__(256) void wcvt_kernel(const float* __restrict__ W1,
                                                   const float* __restrict__ W2,
                                                   uint4* __restrict__ wb) {
  int t = blockIdx.x * 256 + threadIdx.x;   // < 12288 exact
  int m = t >> 11;            // matrix 0..5: layer*2 + (0=W1,1=W2)
  int q = t & 2047;           // 16B chunk within matrix
  int byte = q * 16;
  int row = byte >> 8;
  int inner = byte & 255;
  int isrc = inner ^ ((row & 7) << 4);   // inverse swizzle (involution)
  int k0 = isrc >> 1;
  const float* Wsrc = (m & 1) ? W2 : W1;
  const float* p = Wsrc + ((size_t)(m >> 1) * DD * DD + row * DD + k0);
  float4 f0 = ((const float4*)p)[0], f1 = ((const float4*)p)[1];
  float f[8] = {f0.x, f0.y, f0.z, f0.w, f1.x, f1.y, f1.z, f1.w};
  wb[(size_t)m * 2048 + q] = pack8(f);
}

// ---------- CSR build ----------
__global__ __launch_bounds__(256) void hist_kernel(const int* __restrict__ dst,
                                                   int* __restrict__ counts, int E) {
  int e = blockIdx.x * blockDim.x + threadIdx.x;
  if (e < E) atomicAdd(&counts[dst[e]], 1);
}

__global__ __launch_bounds__(256) void scan1_kernel(const int* __restrict__ counts,
                                                    int* __restrict__ rp,
                                                    int* __restrict__ bsum, int n) {
  int i = blockIdx.x * 256 + threadIdx.x;
  int v = (i < n) ? counts[i] : 0;
  int lane = threadIdx.x & 63, w = threadIdx.x >> 6;
  int s = v;
#pragma unroll
  for (int off = 1; off < 64; off <<= 1) {
    int u = __shfl_up(s, off);
    if (lane >= off) s += u;
  }
  __shared__ int ws[4];
  if (lane == 63) ws[w] = s;
  __syncthreads();
  int add = 0;
#pragma unroll
  for (int k = 0; k < 4; ++k) if (k < w) add += ws[k];
  int incl = s + add;
  if (i < n) rp[i] = incl - v;
  if (threadIdx.x == 255) bsum[blockIdx.x] = incl;
}

__global__ __launch_bounds__(256) void scan2_kernel(int* __restrict__ bsum, int nb) {
  int t = threadIdx.x;
  int v = (t < nb) ? bsum[t] : 0;
  int lane = t & 63, w = t >> 6;
  int s = v;
#pragma unroll
  for (int off = 1; off < 64; off <<= 1) {
    int u = __shfl_up(s, off);
    if (lane >= off) s += u;
  }
  __shared__ int ws[4];
  if (lane == 63) ws[w] = s;
  __syncthreads();
  int add = 0;
#pragma unroll
  for (int k = 0; k < 4; ++k) if (k < w) add += ws[k];
  int incl = s + add;
  if (t < nb) bsum[t] = incl - v;
}

__global__ __launch_bounds__(256) void scan3_kernel(int* __restrict__ rp,
                                                    int* __restrict__ cursor,
                                                    const int* __restrict__ bsum, int n) {
  int i = blockIdx.x * 256 + threadIdx.x;
  if (i < n) {
    int v = rp[i] + bsum[blockIdx.x];
    rp[i] = v;
    cursor[i] = v;
  }
  if (i == 0) rp[n] = EE;
}

__global__ __launch_bounds__(256) void fill_kernel(const int* __restrict__ src,
                                                   const int* __restrict__ dst,
                                                   int* __restrict__ cursor,
                                                   int* __restrict__ col, int E) {
  int e = blockIdx.x * blockDim.x + threadIdx.x;
  if (e < E) {
    int p = atomicAdd(&cursor[dst[e]], 1);
    col[p] = src[e];
  }
}

// ---------- GIN aggregation: 8-deep ILP gather, min-waves=4 (128 VGPR, no spill) ----------
__global__ __launch_bounds__(256, 4) void agg_kernel(const uint4* __restrict__ xin,
                                                     const int* __restrict__ row_ptr,
                                                     const int* __restrict__ colv,
                                                     uint4* __restrict__ agg, int n) {
  int tid = blockIdx.x * 256 + threadIdx.x;
  int node = tid >> 4;
  int c = tid & 15;
  if (node >= n) return;
  float acc[8];
  unpack8(xin[(size_t)node * 16 + c], acc);
  int s = row_ptr[node], e = row_ptr[node + 1];
  int j = s;
  for (; j + 8 <= e; j += 8) {
    int i0 = colv[j],     i1 = colv[j + 1], i2 = colv[j + 2], i3 = colv[j + 3];
    int i4 = colv[j + 4], i5 = colv[j + 5], i6 = colv[j + 6], i7 = colv[j + 7];
    uint4 v0 = xin[(size_t)i0 * 16 + c];
    uint4 v1 = xin[(size_t)i1 * 16 + c];
    uint4 v2 = xin[(size_t)i2 * 16 + c];
    uint4 v3 = xin[(size_t)i3 * 16 + c];
    uint4 v4 = xin[(size_t)i4 * 16 + c];
    uint4 v5 = xin[(size_t)i5 * 16 + c];
    uint4 v6 = xin[(size_t)i6 * 16 + c];
    uint4 v7 = xin[(size_t)i7 * 16 + c];
    acc8(v0, acc); acc8(v1, acc); acc8(v2, acc); acc8(v3, acc);
    acc8(v4, acc); acc8(v5, acc); acc8(v6, acc); acc8(v7, acc);
  }
  for (; j + 2 <= e; j += 2) {
    uint4 v0 = xin[(size_t)colv[j] * 16 + c];
    uint4 v1 = xin[(size_t)colv[j + 1] * 16 + c];
    acc8(v0, acc); acc8(v1, acc);
  }
  if (j < e) acc8(xin[(size_t)colv[j] * 16 + c], acc);
  agg[(size_t)node * 16 + c] = pack8(acc);
}

// ---------- persistent MFMA MLP: 256 blocks, 512 threads, 128-row tiles ----------
// LDS 96KB: W1 32K + W2 32K + X 32K. Weights staged ONCE per block, then the
// block loops over tiles (tile = bid, bid+256, ...): 16MB weight staging/layer
// instead of 50MB, and 8 waves hide the X-stage latency.
__global__ __launch_bounds__(512) void mlp128(
    const uint4* __restrict__ aggb, unsigned short* __restrict__ xout,
    const uint4* __restrict__ w1b, const uint4* __restrict__ w2b,
    const float* __restrict__ b1, const float* __restrict__ bng,
    const float* __restrict__ bnb, const float* __restrict__ bnm,
    const float* __restrict__ bnv, const float* __restrict__ b2, int n) {
  __shared__ __align__(16) char smem[98304];
  char* w1p = smem;           // 32KB bf16 W1, pre-swizzled
  char* w2p = smem + 32768;   // 32KB bf16 W2
  char* xp  = smem + 65536;   // 32KB: 128 rows x 256B, swizzled

  // stage weights once per block (4096 uint4, 512 threads -> 8 iters)
#pragma unroll
  for (int it = 0; it < 8; ++it) {
    int q = it * 512 + threadIdx.x;
    ((uint4*)w1p)[q] = w1b[q];
    ((uint4*)w2p)[q] = w2b[q];
  }

  int lane = threadIdx.x & 63;
  int c = lane & 15;
  int kq = lane >> 4;
  int wave = threadIdx.x >> 6;
  int r0 = wave * 16;          // wave's 16-row sub-tile (8 waves x 16 = 128)

  float b1v[8], sv[8], tv[8], b2v[8];
#pragma unroll
  for (int ni = 0; ni < 8; ++ni) {
    int cc = ni * 16 + c;
    b1v[ni] = b1[cc];
    float s = bng[cc] * rsqrtf(bnv[cc] + 1e-5f);
    sv[ni] = s;
    tv[ni] = bnb[cc] - bnm[cc] * s;
    b2v[ni] = b2[cc];
  }

  for (int tile = blockIdx.x; tile * 128 < n; tile += 256) {
    int base = tile * 128;
    // stage X tile: 2048 chunks of 16B, 4 per thread, swizzled
#pragma unroll
    for (int it = 0; it < 4; ++it) {
      int t = it * 512 + threadIdx.x;
      int row = t >> 4, cc = t & 15;
      int grow = base + row;
      uint4 v = make_uint4(0, 0, 0, 0);
      if (grow < n) v = aggb[(size_t)grow * 16 + cc];
      *(uint4*)(xp + SWZ(row * 256 + cc * 16, row)) = v;
    }
    __syncthreads();   // X staged (and, on first iter, weights staged)

    f32x4 acc[8];
#pragma unroll
    for (int ni = 0; ni < 8; ++ni) acc[ni] = (f32x4){0.f, 0.f, 0.f, 0.f};

    // GEMM1: h = X @ W1^T
#pragma unroll
    for (int ks = 0; ks < 4; ++ks) {
      int row = r0 + c;
      bf16x8 a = *(const bf16x8*)(xp + SWZ(row * 256 + ks * 64 + kq * 16, row));
#pragma unroll
      for (int ni = 0; ni < 8; ++ni) {
        int wr = ni * 16 + c;
        bf16x8 bfr = *(const bf16x8*)(w1p + SWZ(wr * 256 + ks * 64 + kq * 16, wr));
        acc[ni] = __builtin_amdgcn_mfma_f32_16x16x32_bf16(a, bfr, acc[ni], 0, 0, 0);
      }
    }

    // epilogue 1: leaky + BN -> back to X LDS (wave-local rows)
#pragma unroll
    for (int ni = 0; ni < 8; ++ni)
#pragma unroll
      for (int r = 0; r < 4; ++r) {
        float h = acc[ni][r] + b1v[ni];
        h = h >= 0.f ? h : 0.2f * h;
        h = h * sv[ni] + tv[ni];
        int row = r0 + kq * 4 + r;
        *(__bf16*)(xp + SWZ(row * 256 + (ni * 16 + c) * 2, row)) = (__bf16)h;
      }
    __syncthreads();

#pragma unroll
    for (int ni = 0; ni < 8; ++ni) acc[ni] = (f32x4){0.f, 0.f, 0.f, 0.f};

    // GEMM2: x = h @ W2^T
#pragma unroll
    for (int ks = 0; ks < 4; ++ks) {
      int row = r0 + c;
      bf16x8 a = *(const bf16x8*)(xp + SWZ(row * 256 + ks * 64 + kq * 16, row));
#pragma unroll
      for (int ni = 0; ni < 8; ++ni) {
        int wr = ni * 16 + c;
        bf16x8 bfr = *(const bf16x8*)(w2p + SWZ(wr * 256 + ks * 64 + kq * 16, wr));
        acc[ni] = __builtin_amdgcn_mfma_f32_16x16x32_bf16(a, bfr, acc[ni], 0, 0, 0);
      }
    }

    // epilogue 2: leaky -> global bf16
#pragma unroll
    for (int ni = 0; ni < 8; ++ni)
#pragma unroll
      for (int r = 0; r < 4; ++r) {
        float xo = acc[ni][r] + b2v[ni];
        xo = xo >= 0.f ? xo : 0.2f * xo;
        int grow = base + r0 + kq * 4 + r;
        if (grow < n) xout[(size_t)grow * DD + ni * 16 + c] = f2bf(xo);
      }
    __syncthreads();   // GEMM2's xp reads done before next tile restages
  }
}

// ---------- pooling: sorted batch -> run-accumulate, flush on graph change ----------
__global__ __launch_bounds__(256) void pool_kernel(const uint4* __restrict__ x,
                                                   const int* __restrict__ batch,
                                                   float* __restrict__ pooled, int n) {
  int gid = blockIdx.x * 256 + threadIdx.x;
  int grp = gid >> 4, c = gid & 15;
  int n0 = grp * 16;
  if (n0 >= n) return;
  float acc[8] = {0.f, 0.f, 0.f, 0.f, 0.f, 0.f, 0.f, 0.f};
  int curg = batch[n0];
  int end = n0 + 16 < n ? n0 + 16 : n;
  for (int node = n0; node < end; ++node) {
    int g = batch[node];
    if (g != curg) {
      float* p = pooled + (size_t)curg * DD + c * 8;
#pragma unroll
      for (int i = 0; i < 8; ++i) { atomicAdd(p + i, acc[i]); acc[i] = 0.f; }
      curg = g;
    }
    float tmp[8];
    unpack8(x[(size_t)node * 16 + c], tmp);
#pragma unroll
    for (int i = 0; i < 8; ++i) acc[i] += tmp[i];
  }
  float* p = pooled + (size_t)curg * DD + c * 8;
#pragma unroll
  for (int i = 0; i < 8; ++i) atomicAdd(p + i, acc[i]);
}

// ---------- head ----------
__global__ __launch_bounds__(128) void head_kernel(const float* __restrict__ pooled,
    const float* __restrict__ og, const float* __restrict__ ob,
    const float* __restrict__ om, const float* __restrict__ ov,
    const float* __restrict__ fcW, const float* __restrict__ fcb,
    float* __restrict__ out) {
  __shared__ float pb[DD];
  int g = blockIdx.x;
  int t = threadIdx.x;
  float s = og[t] * rsqrtf(ov[t] + 1e-5f);
  pb[t] = (pooled[(size_t)g * DD + t] - om[t]) * s + ob[t];
  __syncthreads();
  if (t < LATD) {
    float acc = fcb[t];
#pragma unroll 8
    for (int d = 0; d < DD; ++d) acc = fmaf(fcW[t * DD + d], pb[d], acc);
    out[(size_t)g * LATD + t] = acc;
  }
}

extern "C" void kernel_launch(void* const* d_in, const int* in_sizes, int n_in,
                              void* d_out, int out_size, void* d_ws, size_t ws_size,
                              hipStream_t stream) {
  const float* x   = (const float*)d_in[0];
  const float* W1  = (const float*)d_in[1];
  const float* b1  = (const float*)d_in[2];
  const float* bng = (const float*)d_in[3];
  const float* bnb = (const float*)d_in[4];
  const float* bnm = (const float*)d_in[5];
  const float* bnv = (const float*)d_in[6];
  const float* W2  = (const float*)d_in[7];
  const float* b2  = (const float*)d_in[8];
  const float* og  = (const float*)d_in[9];
  const float* ob  = (const float*)d_in[10];
  const float* om  = (const float*)d_in[11];
  const float* ov  = (const float*)d_in[12];
  const float* fcW = (const float*)d_in[13];
  const float* fcb = (const float*)d_in[14];
  const int* ei    = (const int*)d_in[15];
  const int* batch = (const int*)d_in[16];
  const int* src  = ei;
  const int* dstp = ei + EE;

  char* ws = (char*)d_ws;
  size_t off = 0;
  auto alloc = [&](size_t bytes) {
    void* p = ws + off;
    off += (bytes + 255) & ~(size_t)255;
    return p;
  };
  unsigned short* xb0  = (unsigned short*)alloc((size_t)NN * DD * 2);
  unsigned short* xb1  = (unsigned short*)alloc((size_t)NN * DD * 2);
  unsigned short* aggb = (unsigned short*)alloc((size_t)NN * DD * 2);
  uint4* wb     = (uint4*)alloc((size_t)6 * 2048 * 16);
  int* row_ptr  = (int*)alloc((NN + 1) * 4);
  int* cursor   = (int*)alloc(NN * 4);
  int* counts   = (int*)alloc(NN * 4);
  int* col      = (int*)alloc(EE * 4);
  int* bsum     = (int*)alloc(256 * 4);
  float* pooled = (float*)alloc(GG * DD * 4);

  hipMemsetAsync(counts, 0, NN * 4, stream);
  hipMemsetAsync(pooled, 0, GG * DD * 4, stream);

  cvt_kernel<<<3125, 256, 0, stream>>>((const float4*)x, (uint4*)xb0);
  wcvt_kernel<<<48, 256, 0, stream>>>(W1, W2, wb);

  const int NB = (NN + 255) / 256;  // 196
  hist_kernel<<<(EE + 255) / 256, 256, 0, stream>>>(dstp, counts, EE);
  scan1_kernel<<<NB, 256, 0, stream>>>(counts, row_ptr, bsum, NN);
  scan2_kernel<<<1, 256, 0, stream>>>(bsum, NB);
  scan3_kernel<<<NB, 256, 0, stream>>>(row_ptr, cursor, bsum, NN);
  fill_kernel<<<(EE + 255) / 256, 256, 0, stream>>>(src, dstp, cursor, col, EE);

  unsigned short* xcur = xb0;
  unsigned short* xnext = xb1;
  for (int i = 0; i < LL; ++i) {
    agg_kernel<<<(NN * 16 + 255) / 256, 256, 0, stream>>>(
        (const uint4*)xcur, row_ptr, col, (uint4*)aggb, NN);
    mlp128<<<256, 512, 0, stream>>>(
        (const uint4*)aggb, xnext,
        wb + (size_t)i * 4096, wb + (size_t)i * 4096 + 2048,
        b1 + i * DD, bng + i * DD, bnb + i * DD, bnm + i * DD, bnv + i * DD,
        b2 + i * DD, NN);
    unsigned short* t = xcur; xcur = xnext; xnext = t;
  }
  pool_kernel<<<(NN * 16 + 255) / 256, 256, 0, stream>>>(
      (const uint4*)xcur, batch, pooled, NN);
  head_kernel<<<GG, 128, 0, stream>>>(pooled, og, ob, om, ov, fcW, fcb, (float*)d_out);
}

// Round 9
// 238.653 us; speedup vs baseline: 1.9752x; 1.0082x over previous
//
#include <hip/hip_runtime.h>
#include <cstdint>
#include <cstddef>

#define NN 50000
#define EE 640000
#define DD 128
#define LL 3
#define GG 256
#define LATD 64

typedef __attribute__((ext_vector_type(8))) __bf16 bf16x8;
typedef __attribute__((ext_vector_type(4))) float f32x4;

__device__ __forceinline__ unsigned short f2bf(float f) {
  __bf16 h = (__bf16)f;
  return __builtin_bit_cast(unsigned short, h);
}
__device__ __forceinline__ float bf2f(unsigned int u16) {
  unsigned int x = u16 << 16;
  return __builtin_bit_cast(float, x);
}
__device__ __forceinline__ void unpack8(uint4 v, float* f) {
  f[0] = bf2f(v.x & 0xffffu); f[1] = bf2f(v.x >> 16);
  f[2] = bf2f(v.y & 0xffffu); f[3] = bf2f(v.y >> 16);
  f[4] = bf2f(v.z & 0xffffu); f[5] = bf2f(v.z >> 16);
  f[6] = bf2f(v.w & 0xffffu); f[7] = bf2f(v.w >> 16);
}
__device__ __forceinline__ void acc8(uint4 v, float* f) {
  f[0] += bf2f(v.x & 0xffffu); f[1] += bf2f(v.x >> 16);
  f[2] += bf2f(v.y & 0xffffu); f[3] += bf2f(v.y >> 16);
  f[4] += bf2f(v.z & 0xffffu); f[5] += bf2f(v.z >> 16);
  f[6] += bf2f(v.w & 0xffffu); f[7] += bf2f(v.w >> 16);
}
__device__ __forceinline__ uint4 pack8(const float* f) {
  uint4 v;
  v.x = f2bf(f[0]) | ((unsigned)f2bf(f[1]) << 16);
  v.y = f2bf(f[2]) | ((unsigned)f2bf(f[3]) << 16);
  v.z = f2bf(f[4]) | ((unsigned)f2bf(f[5]) << 16);
  v.w = f2bf(f[6]) | ((unsigned)f2bf(f[7]) << 16);
  return v;
}

#define SWZ(byte_, row_) ((byte_) ^ (((row_) & 7) << 4))
// counters padded: 1 int per 64B cache line -> same-line atomic serialization
// drops from ~205 ops/line to ~12.8 (cross-XCD atomic ping-pong was fill's 41us)
#define CPAD 4   // index << 4

// ---------- x fp32 -> bf16 ----------
__global__ __launch_bounds__(256) void cvt_kernel(const float4* __restrict__ x,
                                                  uint4* __restrict__ xb) {
  int t = blockIdx.x * 256 + threadIdx.x;   // < 800000 exact
  float4 a = x[t * 2], b = x[t * 2 + 1];
  float f[8] = {a.x, a.y, a.z, a.w, b.x, b.y, b.z, b.w};
  xb[t] = pack8(f);
}

// ---------- weights fp32 -> bf16, pre-swizzled ----------
__global__ __launch_bounds__(256) void wcvt_kernel(const float* __restrict__ W1,
                                                   const float* __restrict__ W2,
                                                   uint4* __restrict__ wb) {
  int t = blockIdx.x * 256 + threadIdx.x;   // < 12288 exact
  int m = t >> 11;
  int q = t & 2047;
  int byte = q * 16;
  int row = byte >> 8;
  int inner = byte & 255;
  int isrc = inner ^ ((row & 7) << 4);
  int k0 = isrc >> 1;
  const float* Wsrc = (m & 1) ? W2 : W1;
  const float* p = Wsrc + ((size_t)(m >> 1) * DD * DD + row * DD + k0);
  float4 f0 = ((const float4*)p)[0], f1 = ((const float4*)p)[1];
  float f[8] = {f0.x, f0.y, f0.z, f0.w, f1.x, f1.y, f1.z, f1.w};
  wb[(size_t)m * 2048 + q] = pack8(f);
}

// ---------- CSR build (padded counters) ----------
__global__ __launch_bounds__(256) void hist_kernel(const int* __restrict__ dst,
                                                   int* __restrict__ counts, int E) {
  int e = blockIdx.x * blockDim.x + threadIdx.x;
  if (e < E) atomicAdd(&counts[dst[e] << CPAD], 1);
}

__global__ __launch_bounds__(256) void scan1_kernel(const int* __restrict__ counts,
                                                    int* __restrict__ rp,
                                                    int* __restrict__ bsum, int n) {
  int i = blockIdx.x * 256 + threadIdx.x;
  int v = (i < n) ? counts[i << CPAD] : 0;
  int lane = threadIdx.x & 63, w = threadIdx.x >> 6;
  int s = v;
#pragma unroll
  for (int off = 1; off < 64; off <<= 1) {
    int u = __shfl_up(s, off);
    if (lane >= off) s += u;
  }
  __shared__ int ws[4];
  if (lane == 63) ws[w] = s;
  __syncthreads();
  int add = 0;
#pragma unroll
  for (int k = 0; k < 4; ++k) if (k < w) add += ws[k];
  int incl = s + add;
  if (i < n) rp[i] = incl - v;
  if (threadIdx.x == 255) bsum[blockIdx.x] = incl;
}

__global__ __launch_bounds__(256) void scan2_kernel(int* __restrict__ bsum, int nb) {
  int t = threadIdx.x;
  int v = (t < nb) ? bsum[t] : 0;
  int lane = t & 63, w = t >> 6;
  int s = v;
#pragma unroll
  for (int off = 1; off < 64; off <<= 1) {
    int u = __shfl_up(s, off);
    if (lane >= off) s += u;
  }
  __shared__ int ws[4];
  if (lane == 63) ws[w] = s;
  __syncthreads();
  int add = 0;
#pragma unroll
  for (int k = 0; k < 4; ++k) if (k < w) add += ws[k];
  int incl = s + add;
  if (t < nb) bsum[t] = incl - v;
}

__global__ __launch_bounds__(256) void scan3_kernel(int* __restrict__ rp,
                                                    int* __restrict__ cursor,
                                                    const int* __restrict__ bsum, int n) {
  int i = blockIdx.x * 256 + threadIdx.x;
  if (i < n) {
    int v = rp[i] + bsum[blockIdx.x];
    rp[i] = v;
    cursor[i << CPAD] = v;
  }
  if (i == 0) rp[n] = EE;
}

__global__ __launch_bounds__(256) void fill_kernel(const int* __restrict__ src,
                                                   const int* __restrict__ dst,
                                                   int* __restrict__ cursor,
                                                   int* __restrict__ col, int E) {
  int e = blockIdx.x * blockDim.x + threadIdx.x;
  if (e < E) {
    int p = atomicAdd(&cursor[dst[e] << CPAD], 1);
    col[p] = src[e];
  }
}

// ---------- GIN aggregation: 32 lanes/node (2 halves x 16 dims), 4-deep ILP ----------
// Halves the serial gather chain per thread; shfl_xor(16) combines halves.
__global__ __launch_bounds__(256, 8) void agg_kernel(const uint4* __restrict__ xin,
                                                     const int* __restrict__ row_ptr,
                                                     const int* __restrict__ colv,
                                                     uint4* __restrict__ agg, int n) {
  int tid = blockIdx.x * 256 + threadIdx.x;
  int node = tid >> 5;
  int c = tid & 15;
  int half = (tid >> 4) & 1;
  if (node >= n) return;
  float acc[8] = {0.f, 0.f, 0.f, 0.f, 0.f, 0.f, 0.f, 0.f};
  if (!half) unpack8(xin[(size_t)node * 16 + c], acc);  // self term once
  int s = row_ptr[node], e = row_ptr[node + 1];
  int j = s + half;                       // this half takes every 2nd edge
  for (; j + 6 < e; j += 8) {
    int i0 = colv[j], i1 = colv[j + 2], i2 = colv[j + 4], i3 = colv[j + 6];
    uint4 v0 = xin[(size_t)i0 * 16 + c];
    uint4 v1 = xin[(size_t)i1 * 16 + c];
    uint4 v2 = xin[(size_t)i2 * 16 + c];
    uint4 v3 = xin[(size_t)i3 * 16 + c];
    acc8(v0, acc); acc8(v1, acc); acc8(v2, acc); acc8(v3, acc);
  }
  for (; j < e; j += 2) acc8(xin[(size_t)colv[j] * 16 + c], acc);
  // combine halves (lane ^ 16 swaps half0<->half1 within the 32-lane node group)
#pragma unroll
  for (int i = 0; i < 8; ++i) acc[i] += __shfl_xor(acc[i], 16);
  if (!half) agg[(size_t)node * 16 + c] = pack8(acc);
}

// ---------- persistent MFMA MLP: 256 blocks, 512 threads, 128-row tiles ----------
__global__ __launch_bounds__(512) void mlp128(
    const uint4* __restrict__ aggb, unsigned short* __restrict__ xout,
    const uint4* __restrict__ w1b, const uint4* __restrict__ w2b,
    const float* __restrict__ b1, const float* __restrict__ bng,
    const float* __restrict__ bnb, const float* __restrict__ bnm,
    const float* __restrict__ bnv, const float* __restrict__ b2, int n) {
  __shared__ __align__(16) char smem[98304];
  char* w1p = smem;
  char* w2p = smem + 32768;
  char* xp  = smem + 65536;

#pragma unroll
  for (int it = 0; it < 8; ++it) {
    int q = it * 512 + threadIdx.x;
    ((uint4*)w1p)[q] = w1b[q];
    ((uint4*)w2p)[q] = w2b[q];
  }

  int lane = threadIdx.x & 63;
  int c = lane & 15;
  int kq = lane >> 4;
  int wave = threadIdx.x >> 6;
  int r0 = wave * 16;

  float b1v[8], sv[8], tv[8], b2v[8];
#pragma unroll
  for (int ni = 0; ni < 8; ++ni) {
    int cc = ni * 16 + c;
    b1v[ni] = b1[cc];
    float s = bng[cc] * rsqrtf(bnv[cc] + 1e-5f);
    sv[ni] = s;
    tv[ni] = bnb[cc] - bnm[cc] * s;
    b2v[ni] = b2[cc];
  }

  for (int tile = blockIdx.x; tile * 128 < n; tile += 256) {
    int base = tile * 128;
#pragma unroll
    for (int it = 0; it < 4; ++it) {
      int t = it * 512 + threadIdx.x;
      int row = t >> 4, cc = t & 15;
      int grow = base + row;
      uint4 v = make_uint4(0, 0, 0, 0);
      if (grow < n) v = aggb[(size_t)grow * 16 + cc];
      *(uint4*)(xp + SWZ(row * 256 + cc * 16, row)) = v;
    }
    __syncthreads();

    f32x4 acc[8];
#pragma unroll
    for (int ni = 0; ni < 8; ++ni) acc[ni] = (f32x4){0.f, 0.f, 0.f, 0.f};

#pragma unroll
    for (int ks = 0; ks < 4; ++ks) {
      int row = r0 + c;
      bf16x8 a = *(const bf16x8*)(xp + SWZ(row * 256 + ks * 64 + kq * 16, row));
#pragma unroll
      for (int ni = 0; ni < 8; ++ni) {
        int wr = ni * 16 + c;
        bf16x8 bfr = *(const bf16x8*)(w1p + SWZ(wr * 256 + ks * 64 + kq * 16, wr));
        acc[ni] = __builtin_amdgcn_mfma_f32_16x16x32_bf16(a, bfr, acc[ni], 0, 0, 0);
      }
    }

#pragma unroll
    for (int ni = 0; ni < 8; ++ni)
#pragma unroll
      for (int r = 0; r < 4; ++r) {
        float h = acc[ni][r] + b1v[ni];
        h = h >= 0.f ? h : 0.2f * h;
        h = h * sv[ni] + tv[ni];
        int row = r0 + kq * 4 + r;
        *(__bf16*)(xp + SWZ(row * 256 + (ni * 16 + c) * 2, row)) = (__bf16)h;
      }
    __syncthreads();

#pragma unroll
    for (int ni = 0; ni < 8; ++ni) acc[ni] = (f32x4){0.f, 0.f, 0.f, 0.f};

#pragma unroll
    for (int ks = 0; ks < 4; ++ks) {
      int row = r0 + c;
      bf16x8 a = *(const bf16x8*)(xp + SWZ(row * 256 + ks * 64 + kq * 16, row));
#pragma unroll
      for (int ni = 0; ni < 8; ++ni) {
        int wr = ni * 16 + c;
        bf16x8 bfr = *(const bf16x8*)(w2p + SWZ(wr * 256 + ks * 64 + kq * 16, wr));
        acc[ni] = __builtin_amdgcn_mfma_f32_16x16x32_bf16(a, bfr, acc[ni], 0, 0, 0);
      }
    }

#pragma unroll
    for (int ni = 0; ni < 8; ++ni)
#pragma unroll
      for (int r = 0; r < 4; ++r) {
        float xo = acc[ni][r] + b2v[ni];
        xo = xo >= 0.f ? xo : 0.2f * xo;
        int grow = base + r0 + kq * 4 + r;
        if (grow < n) xout[(size_t)grow * DD + ni * 16 + c] = f2bf(xo);
      }
    __syncthreads();
  }
}

// ---------- pooling ----------
__global__ __launch_bounds__(256) void pool_kernel(const uint4* __restrict__ x,
                                                   const int* __restrict__ batch,
                                                   float* __restrict__ pooled, int n) {
  int gid = blockIdx.x * 256 + threadIdx.x;
  int grp = gid >> 4, c = gid & 15;
  int n0 = grp * 16;
  if (n0 >= n) return;
  float acc[8] = {0.f, 0.f, 0.f, 0.f, 0.f, 0.f, 0.f, 0.f};
  int curg = batch[n0];
  int end = n0 + 16 < n ? n0 + 16 : n;
  for (int node = n0; node < end; ++node) {
    int g = batch[node];
    if (g != curg) {
      float* p = pooled + (size_t)curg * DD + c * 8;
#pragma unroll
      for (int i = 0; i < 8; ++i) { atomicAdd(p + i, acc[i]); acc[i] = 0.f; }
      curg = g;
    }
    float tmp[8];
    unpack8(x[(size_t)node * 16 + c], tmp);
#pragma unroll
    for (int i = 0; i < 8; ++i) acc[i] += tmp[i];
  }
  float* p = pooled + (size_t)curg * DD + c * 8;
#pragma unroll
  for (int i = 0; i < 8; ++i) atomicAdd(p + i, acc[i]);
}

// ---------- head ----------
__global__ __launch_bounds__(128) void head_kernel(const float* __restrict__ pooled,
    const float* __restrict__ og, const float* __restrict__ ob,
    const float* __restrict__ om, const float* __restrict__ ov,
    const float* __restrict__ fcW, const float* __restrict__ fcb,
    float* __restrict__ out) {
  __shared__ float pb[DD];
  int g = blockIdx.x;
  int t = threadIdx.x;
  float s = og[t] * rsqrtf(ov[t] + 1e-5f);
  pb[t] = (pooled[(size_t)g * DD + t] - om[t]) * s + ob[t];
  __syncthreads();
  if (t < LATD) {
    float acc = fcb[t];
#pragma unroll 8
    for (int d = 0; d < DD; ++d) acc = fmaf(fcW[t * DD + d], pb[d], acc);
    out[(size_t)g * LATD + t] = acc;
  }
}

extern "C" void kernel_launch(void* const* d_in, const int* in_sizes, int n_in,
                              void* d_out, int out_size, void* d_ws, size_t ws_size,
                              hipStream_t stream) {
  const float* x   = (const float*)d_in[0];
  const float* W1  = (const float*)d_in[1];
  const float* b1  = (const float*)d_in[2];
  const float* bng = (const float*)d_in[3];
  const float* bnb = (const float*)d_in[4];
  const float* bnm = (const float*)d_in[5];
  const float* bnv = (const float*)d_in[6];
  const float* W2  = (const float*)d_in[7];
  const float* b2  = (const float*)d_in[8];
  const float* og  = (const float*)d_in[9];
  const float* ob  = (const float*)d_in[10];
  const float* om  = (const float*)d_in[11];
  const float* ov  = (const float*)d_in[12];
  const float* fcW = (const float*)d_in[13];
  const float* fcb = (const float*)d_in[14];
  const int* ei    = (const int*)d_in[15];
  const int* batch = (const int*)d_in[16];
  const int* src  = ei;
  const int* dstp = ei + EE;

  char* ws = (char*)d_ws;
  size_t off = 0;
  auto alloc = [&](size_t bytes) {
    void* p = ws + off;
    off += (bytes + 255) & ~(size_t)255;
    return p;
  };
  unsigned short* xb0  = (unsigned short*)alloc((size_t)NN * DD * 2);
  unsigned short* xb1  = (unsigned short*)alloc((size_t)NN * DD * 2);
  unsigned short* aggb = (unsigned short*)alloc((size_t)NN * DD * 2);
  uint4* wb     = (uint4*)alloc((size_t)6 * 2048 * 16);
  int* row_ptr  = (int*)alloc((NN + 1) * 4);
  int* cursor   = (int*)alloc((size_t)NN * 64);   // padded: 1 int / 64B line
  int* counts   = (int*)alloc((size_t)NN * 64);   // padded
  int* col      = (int*)alloc(EE * 4);
  int* bsum     = (int*)alloc(256 * 4);
  float* pooled = (float*)alloc(GG * DD * 4);

  hipMemsetAsync(counts, 0, (size_t)NN * 64, stream);
  hipMemsetAsync(pooled, 0, GG * DD * 4, stream);

  cvt_kernel<<<3125, 256, 0, stream>>>((const float4*)x, (uint4*)xb0);
  wcvt_kernel<<<48, 256, 0, stream>>>(W1, W2, wb);

  const int NB = (NN + 255) / 256;  // 196
  hist_kernel<<<(EE + 255) / 256, 256, 0, stream>>>(dstp, counts, EE);
  scan1_kernel<<<NB, 256, 0, stream>>>(counts, row_ptr, bsum, NN);
  scan2_kernel<<<1, 256, 0, stream>>>(bsum, NB);
  scan3_kernel<<<NB, 256, 0, stream>>>(row_ptr, cursor, bsum, NN);
  fill_kernel<<<(EE + 255) / 256, 256, 0, stream>>>(src, dstp, cursor, col, EE);

  unsigned short* xcur = xb0;
  unsigned short* xnext = xb1;
  for (int i = 0; i < LL; ++i) {
    agg_kernel<<<(NN * 32 + 255) / 256, 256, 0, stream>>>(
        (const uint4*)xcur, row_ptr, col, (uint4*)aggb, NN);
    mlp128<<<256, 512, 0, stream>>>(
        (const uint4*)aggb, xnext,
        wb + (size_t)i * 4096, wb + (size_t)i * 4096 + 2048,
        b1 + i * DD, bng + i * DD, bnb + i * DD, bnm + i * DD, bnv + i * DD,
        b2 + i * DD, NN);
    unsigned short* t = xcur; xcur = xnext; xnext = t;
  }
  pool_kernel<<<(NN * 16 + 255) / 256, 256, 0, stream>>>(
      (const uint4*)xcur, batch, pooled, NN);
  head_kernel<<<GG, 128, 0, stream>>>(pooled, og, ob, om, ov, fcW, fcb, (float*)d_out);
}

// Round 10
// 232.038 us; speedup vs baseline: 2.0315x; 1.0285x over previous
//
#include <hip/hip_runtime.h>
#include <cstdint>
#include <cstddef>

#define NN 50000
#define EE 640000
#define DD 128
#define LL 3
#define GG 256
#define LATD 64

typedef __attribute__((ext_vector_type(8))) __bf16 bf16x8;
typedef __attribute__((ext_vector_type(4))) float f32x4;

__device__ __forceinline__ unsigned short f2bf(float f) {
  __bf16 h = (__bf16)f;
  return __builtin_bit_cast(unsigned short, h);
}
__device__ __forceinline__ float bf2f(unsigned int u16) {
  unsigned int x = u16 << 16;
  return __builtin_bit_cast(float, x);
}
__device__ __forceinline__ void unpack8(uint4 v, float* f) {
  f[0] = bf2f(v.x & 0xffffu); f[1] = bf2f(v.x >> 16);
  f[2] = bf2f(v.y & 0xffffu); f[3] = bf2f(v.y >> 16);
  f[4] = bf2f(v.z & 0xffffu); f[5] = bf2f(v.z >> 16);
  f[6] = bf2f(v.w & 0xffffu); f[7] = bf2f(v.w >> 16);
}
__device__ __forceinline__ void acc8(uint4 v, float* f) {
  f[0] += bf2f(v.x & 0xffffu); f[1] += bf2f(v.x >> 16);
  f[2] += bf2f(v.y & 0xffffu); f[3] += bf2f(v.y >> 16);
  f[4] += bf2f(v.z & 0xffffu); f[5] += bf2f(v.z >> 16);
  f[6] += bf2f(v.w & 0xffffu); f[7] += bf2f(v.w >> 16);
}
__device__ __forceinline__ uint4 pack8(const float* f) {
  uint4 v;
  v.x = f2bf(f[0]) | ((unsigned)f2bf(f[1]) << 16);
  v.y = f2bf(f[2]) | ((unsigned)f2bf(f[3]) << 16);
  v.z = f2bf(f[4]) | ((unsigned)f2bf(f[5]) << 16);
  v.w = f2bf(f[6]) | ((unsigned)f2bf(f[7]) << 16);
  return v;
}

#define SWZ(byte_, row_) ((byte_) ^ (((row_) & 7) << 4))
// counters padded: 1 int per 64B cache line (atomic same-line serialization fix)
#define CPAD 4

// ---------- prep: x cvt | weights cvt pre-swizzled | degree hist (padded) ----------
#define CVT_BLK 3125   // 800000 threads exact
#define WCV_BLK 48     // 12288 threads exact
#define HIST_BLK 2500  // 640000 threads exact
__global__ __launch_bounds__(256) void prep_kernel(
    const float4* __restrict__ x, uint4* __restrict__ xb,
    const float* __restrict__ W1, const float* __restrict__ W2,
    uint4* __restrict__ wb, const int* __restrict__ dst,
    int* __restrict__ counts) {
  int b = blockIdx.x;
  if (b < CVT_BLK) {
    int t = b * 256 + threadIdx.x;
    float4 a = x[t * 2], bb = x[t * 2 + 1];
    float f[8] = {a.x, a.y, a.z, a.w, bb.x, bb.y, bb.z, bb.w};
    xb[t] = pack8(f);
  } else if (b < CVT_BLK + WCV_BLK) {
    int t = (b - CVT_BLK) * 256 + threadIdx.x;
    int m = t >> 11;            // matrix 0..5
    int q = t & 2047;           // 16B chunk
    int byte = q * 16;
    int row = byte >> 8;
    int inner = byte & 255;
    int isrc = inner ^ ((row & 7) << 4);
    int k0 = isrc >> 1;
    const float* Wsrc = (m & 1) ? W2 : W1;
    const float* p = Wsrc + ((size_t)(m >> 1) * DD * DD + row * DD + k0);
    float4 f0 = ((const float4*)p)[0], f1 = ((const float4*)p)[1];
    float f[8] = {f0.x, f0.y, f0.z, f0.w, f1.x, f1.y, f1.z, f1.w};
    wb[(size_t)m * 2048 + q] = pack8(f);
  } else {
    int e = (b - CVT_BLK - WCV_BLK) * 256 + threadIdx.x;
    atomicAdd(&counts[dst[e] << CPAD], 1);
  }
}

// ---------- CSR scans (padded counter reads/writes) ----------
__global__ __launch_bounds__(256) void scan1_kernel(const int* __restrict__ counts,
                                                    int* __restrict__ rp,
                                                    int* __restrict__ bsum, int n) {
  int i = blockIdx.x * 256 + threadIdx.x;
  int v = (i < n) ? counts[i << CPAD] : 0;
  int lane = threadIdx.x & 63, w = threadIdx.x >> 6;
  int s = v;
#pragma unroll
  for (int off = 1; off < 64; off <<= 1) {
    int u = __shfl_up(s, off);
    if (lane >= off) s += u;
  }
  __shared__ int ws[4];
  if (lane == 63) ws[w] = s;
  __syncthreads();
  int add = 0;
#pragma unroll
  for (int k = 0; k < 4; ++k) if (k < w) add += ws[k];
  int incl = s + add;
  if (i < n) rp[i] = incl - v;
  if (threadIdx.x == 255) bsum[blockIdx.x] = incl;
}

__global__ __launch_bounds__(256) void scan2_kernel(int* __restrict__ bsum, int nb) {
  int t = threadIdx.x;
  int v = (t < nb) ? bsum[t] : 0;
  int lane = t & 63, w = t >> 6;
  int s = v;
#pragma unroll
  for (int off = 1; off < 64; off <<= 1) {
    int u = __shfl_up(s, off);
    if (lane >= off) s += u;
  }
  __shared__ int ws[4];
  if (lane == 63) ws[w] = s;
  __syncthreads();
  int add = 0;
#pragma unroll
  for (int k = 0; k < 4; ++k) if (k < w) add += ws[k];
  int incl = s + add;
  if (t < nb) bsum[t] = incl - v;
}

__global__ __launch_bounds__(256) void scan3_kernel(int* __restrict__ rp,
                                                    int* __restrict__ cursor,
                                                    const int* __restrict__ bsum, int n) {
  int i = blockIdx.x * 256 + threadIdx.x;
  if (i < n) {
    int v = rp[i] + bsum[blockIdx.x];
    rp[i] = v;
    cursor[i << CPAD] = v;
  }
  if (i == 0) rp[n] = EE;
}

__global__ __launch_bounds__(256) void fill_kernel(const int* __restrict__ src,
                                                   const int* __restrict__ dst,
                                                   int* __restrict__ cursor,
                                                   int* __restrict__ col, int E) {
  int e = blockIdx.x * blockDim.x + threadIdx.x;
  if (e < E) {
    int p = atomicAdd(&cursor[dst[e] << CPAD], 1);
    col[p] = src[e];
  }
}

// ---------- GIN aggregation: r7-proven — 16 lanes/node, 8-deep ILP, (256,4) ----------
__global__ __launch_bounds__(256, 4) void agg_kernel(const uint4* __restrict__ xin,
                                                     const int* __restrict__ row_ptr,
                                                     const int* __restrict__ colv,
                                                     uint4* __restrict__ agg, int n) {
  int tid = blockIdx.x * 256 + threadIdx.x;
  int node = tid >> 4;
  int c = tid & 15;
  if (node >= n) return;
  float acc[8];
  unpack8(xin[(size_t)node * 16 + c], acc);
  int s = row_ptr[node], e = row_ptr[node + 1];
  int j = s;
  for (; j + 8 <= e; j += 8) {
    int i0 = colv[j],     i1 = colv[j + 1], i2 = colv[j + 2], i3 = colv[j + 3];
    int i4 = colv[j + 4], i5 = colv[j + 5], i6 = colv[j + 6], i7 = colv[j + 7];
    uint4 v0 = xin[(size_t)i0 * 16 + c];
    uint4 v1 = xin[(size_t)i1 * 16 + c];
    uint4 v2 = xin[(size_t)i2 * 16 + c];
    uint4 v3 = xin[(size_t)i3 * 16 + c];
    uint4 v4 = xin[(size_t)i4 * 16 + c];
    uint4 v5 = xin[(size_t)i5 * 16 + c];
    uint4 v6 = xin[(size_t)i6 * 16 + c];
    uint4 v7 = xin[(size_t)i7 * 16 + c];
    acc8(v0, acc); acc8(v1, acc); acc8(v2, acc); acc8(v3, acc);
    acc8(v4, acc); acc8(v5, acc); acc8(v6, acc); acc8(v7, acc);
  }
  for (; j + 2 <= e; j += 2) {
    uint4 v0 = xin[(size_t)colv[j] * 16 + c];
    uint4 v1 = xin[(size_t)colv[j + 1] * 16 + c];
    acc8(v0, acc); acc8(v1, acc);
  }
  if (j < e) acc8(xin[(size_t)colv[j] * 16 + c], acc);
  agg[(size_t)node * 16 + c] = pack8(acc);
}

// ---------- persistent MFMA MLP: 256 blocks, 512 threads, 128-row tiles ----------
__global__ __launch_bounds__(512) void mlp128(
    const uint4* __restrict__ aggb, unsigned short* __restrict__ xout,
    const uint4* __restrict__ w1b, const uint4* __restrict__ w2b,
    const float* __restrict__ b1, const float* __restrict__ bng,
    const float* __restrict__ bnb, const float* __restrict__ bnm,
    const float* __restrict__ bnv, const float* __restrict__ b2, int n) {
  __shared__ __align__(16) char smem[98304];
  char* w1p = smem;
  char* w2p = smem + 32768;
  char* xp  = smem + 65536;

#pragma unroll
  for (int it = 0; it < 8; ++it) {
    int q = it * 512 + threadIdx.x;
    ((uint4*)w1p)[q] = w1b[q];
    ((uint4*)w2p)[q] = w2b[q];
  }

  int lane = threadIdx.x & 63;
  int c = lane & 15;
  int kq = lane >> 4;
  int wave = threadIdx.x >> 6;
  int r0 = wave * 16;

  float b1v[8], sv[8], tv[8], b2v[8];
#pragma unroll
  for (int ni = 0; ni < 8; ++ni) {
    int cc = ni * 16 + c;
    b1v[ni] = b1[cc];
    float s = bng[cc] * rsqrtf(bnv[cc] + 1e-5f);
    sv[ni] = s;
    tv[ni] = bnb[cc] - bnm[cc] * s;
    b2v[ni] = b2[cc];
  }

  for (int tile = blockIdx.x; tile * 128 < n; tile += 256) {
    int base = tile * 128;
#pragma unroll
    for (int it = 0; it < 4; ++it) {
      int t = it * 512 + threadIdx.x;
      int row = t >> 4, cc = t & 15;
      int grow = base + row;
      uint4 v = make_uint4(0, 0, 0, 0);
      if (grow < n) v = aggb[(size_t)grow * 16 + cc];
      *(uint4*)(xp + SWZ(row * 256 + cc * 16, row)) = v;
    }
    __syncthreads();

    f32x4 acc[8];
#pragma unroll
    for (int ni = 0; ni < 8; ++ni) acc[ni] = (f32x4){0.f, 0.f, 0.f, 0.f};

#pragma unroll
    for (int ks = 0; ks < 4; ++ks) {
      int row = r0 + c;
      bf16x8 a = *(const bf16x8*)(xp + SWZ(row * 256 + ks * 64 + kq * 16, row));
#pragma unroll
      for (int ni = 0; ni < 8; ++ni) {
        int wr = ni * 16 + c;
        bf16x8 bfr = *(const bf16x8*)(w1p + SWZ(wr * 256 + ks * 64 + kq * 16, wr));
        acc[ni] = __builtin_amdgcn_mfma_f32_16x16x32_bf16(a, bfr, acc[ni], 0, 0, 0);
      }
    }

#pragma unroll
    for (int ni = 0; ni < 8; ++ni)
#pragma unroll
      for (int r = 0; r < 4; ++r) {
        float h = acc[ni][r] + b1v[ni];
        h = h >= 0.f ? h : 0.2f * h;
        h = h * sv[ni] + tv[ni];
        int row = r0 + kq * 4 + r;
        *(__bf16*)(xp + SWZ(row * 256 + (ni * 16 + c) * 2, row)) = (__bf16)h;
      }
    __syncthreads();

#pragma unroll
    for (int ni = 0; ni < 8; ++ni) acc[ni] = (f32x4){0.f, 0.f, 0.f, 0.f};

#pragma unroll
    for (int ks = 0; ks < 4; ++ks) {
      int row = r0 + c;
      bf16x8 a = *(const bf16x8*)(xp + SWZ(row * 256 + ks * 64 + kq * 16, row));
#pragma unroll
      for (int ni = 0; ni < 8; ++ni) {
        int wr = ni * 16 + c;
        bf16x8 bfr = *(const bf16x8*)(w2p + SWZ(wr * 256 + ks * 64 + kq * 16, wr));
        acc[ni] = __builtin_amdgcn_mfma_f32_16x16x32_bf16(a, bfr, acc[ni], 0, 0, 0);
      }
    }

#pragma unroll
    for (int ni = 0; ni < 8; ++ni)
#pragma unroll
      for (int r = 0; r < 4; ++r) {
        float xo = acc[ni][r] + b2v[ni];
        xo = xo >= 0.f ? xo : 0.2f * xo;
        int grow = base + r0 + kq * 4 + r;
        if (grow < n) xout[(size_t)grow * DD + ni * 16 + c] = f2bf(xo);
      }
    __syncthreads();
  }
}

// ---------- pooling ----------
__global__ __launch_bounds__(256) void pool_kernel(const uint4* __restrict__ x,
                                                   const int* __restrict__ batch,
                                                   float* __restrict__ pooled, int n) {
  int gid = blockIdx.x * 256 + threadIdx.x;
  int grp = gid >> 4, c = gid & 15;
  int n0 = grp * 16;
  if (n0 >= n) return;
  float acc[8] = {0.f, 0.f, 0.f, 0.f, 0.f, 0.f, 0.f, 0.f};
  int curg = batch[n0];
  int end = n0 + 16 < n ? n0 + 16 : n;
  for (int node = n0; node < end; ++node) {
    int g = batch[node];
    if (g != curg) {
      float* p = pooled + (size_t)curg * DD + c * 8;
#pragma unroll
      for (int i = 0; i < 8; ++i) { atomicAdd(p + i, acc[i]); acc[i] = 0.f; }
      curg = g;
    }
    float tmp[8];
    unpack8(x[(size_t)node * 16 + c], tmp);
#pragma unroll
    for (int i = 0; i < 8; ++i) acc[i] += tmp[i];
  }
  float* p = pooled + (size_t)curg * DD + c * 8;
#pragma unroll
  for (int i = 0; i < 8; ++i) atomicAdd(p + i, acc[i]);
}

// ---------- head ----------
__global__ __launch_bounds__(128) void head_kernel(const float* __restrict__ pooled,
    const float* __restrict__ og, const float* __restrict__ ob,
    const float* __restrict__ om, const float* __restrict__ ov,
    const float* __restrict__ fcW, const float* __restrict__ fcb,
    float* __restrict__ out) {
  __shared__ float pb[DD];
  int g = blockIdx.x;
  int t = threadIdx.x;
  float s = og[t] * rsqrtf(ov[t] + 1e-5f);
  pb[t] = (pooled[(size_t)g * DD + t] - om[t]) * s + ob[t];
  __syncthreads();
  if (t < LATD) {
    float acc = fcb[t];
#pragma unroll 8
    for (int d = 0; d < DD; ++d) acc = fmaf(fcW[t * DD + d], pb[d], acc);
    out[(size_t)g * LATD + t] = acc;
  }
}

extern "C" void kernel_launch(void* const* d_in, const int* in_sizes, int n_in,
                              void* d_out, int out_size, void* d_ws, size_t ws_size,
                              hipStream_t stream) {
  const float* x   = (const float*)d_in[0];
  const float* W1  = (const float*)d_in[1];
  const float* b1  = (const float*)d_in[2];
  const float* bng = (const float*)d_in[3];
  const float* bnb = (const float*)d_in[4];
  const float* bnm = (const float*)d_in[5];
  const float* bnv = (const float*)d_in[6];
  const float* W2  = (const float*)d_in[7];
  const float* b2  = (const float*)d_in[8];
  const float* og  = (const float*)d_in[9];
  const float* ob  = (const float*)d_in[10];
  const float* om  = (const float*)d_in[11];
  const float* ov  = (const float*)d_in[12];
  const float* fcW = (const float*)d_in[13];
  const float* fcb = (const float*)d_in[14];
  const int* ei    = (const int*)d_in[15];
  const int* batch = (const int*)d_in[16];
  const int* src  = ei;
  const int* dstp = ei + EE;

  char* ws = (char*)d_ws;
  size_t off = 0;
  auto alloc = [&](size_t bytes) {
    void* p = ws + off;
    off += (bytes + 255) & ~(size_t)255;
    return p;
  };
  unsigned short* xb0  = (unsigned short*)alloc((size_t)NN * DD * 2);
  unsigned short* xb1  = (unsigned short*)alloc((size_t)NN * DD * 2);
  unsigned short* aggb = (unsigned short*)alloc((size_t)NN * DD * 2);
  uint4* wb     = (uint4*)alloc((size_t)6 * 2048 * 16);
  int* row_ptr  = (int*)alloc((NN + 1) * 4);
  int* cursor   = (int*)alloc((size_t)NN * 64);   // padded: 1 int / 64B line
  int* counts   = (int*)alloc((size_t)NN * 64);   // padded
  int* col      = (int*)alloc(EE * 4);
  int* bsum     = (int*)alloc(256 * 4);
  float* pooled = (float*)alloc(GG * DD * 4);

  hipMemsetAsync(counts, 0, (size_t)NN * 64, stream);
  hipMemsetAsync(pooled, 0, GG * DD * 4, stream);

  prep_kernel<<<CVT_BLK + WCV_BLK + HIST_BLK, 256, 0, stream>>>(
      (const float4*)x, (uint4*)xb0, W1, W2, wb, dstp, counts);

  const int NB = (NN + 255) / 256;  // 196
  scan1_kernel<<<NB, 256, 0, stream>>>(counts, row_ptr, bsum, NN);
  scan2_kernel<<<1, 256, 0, stream>>>(bsum, NB);
  scan3_kernel<<<NB, 256, 0, stream>>>(row_ptr, cursor, bsum, NN);
  fill_kernel<<<(EE + 255) / 256, 256, 0, stream>>>(src, dstp, cursor, col, EE);

  unsigned short* xcur = xb0;
  unsigned short* xnext = xb1;
  for (int i = 0; i < LL; ++i) {
    agg_kernel<<<(NN * 16 + 255) / 256, 256, 0, stream>>>(
        (const uint4*)xcur, row_ptr, col, (uint4*)aggb, NN);
    mlp128<<<256, 512, 0, stream>>>(
        (const uint4*)aggb, xnext,
        wb + (size_t)i * 4096, wb + (size_t)i * 4096 + 2048,
        b1 + i * DD, bng + i * DD, bnb + i * DD, bnm + i * DD, bnv + i * DD,
        b2 + i * DD, NN);
    unsigned short* t = xcur; xcur = xnext; xnext = t;
  }
  pool_kernel<<<(NN * 16 + 255) / 256, 256, 0, stream>>>(
      (const uint4*)xcur, batch, pooled, NN);
  head_kernel<<<GG, 128, 0, stream>>>(pooled, og, ob, om, ov, fcW, fcb, (float*)d_out);
}

// Round 11
// 219.915 us; speedup vs baseline: 2.1435x; 1.0551x over previous
//
#include <hip/hip_runtime.h>
#include <cstdint>
#include <cstddef>

#define NN 50000
#define EE 640000
#define DD 128
#define LL 3
#define GG 256
#define LATD 64

typedef __attribute__((ext_vector_type(8))) __bf16 bf16x8;
typedef __attribute__((ext_vector_type(4))) float f32x4;

__device__ __forceinline__ unsigned short f2bf(float f) {
  __bf16 h = (__bf16)f;
  return __builtin_bit_cast(unsigned short, h);
}
__device__ __forceinline__ float bf2f(unsigned int u16) {
  unsigned int x = u16 << 16;
  return __builtin_bit_cast(float, x);
}
__device__ __forceinline__ void unpack8(uint4 v, float* f) {
  f[0] = bf2f(v.x & 0xffffu); f[1] = bf2f(v.x >> 16);
  f[2] = bf2f(v.y & 0xffffu); f[3] = bf2f(v.y >> 16);
  f[4] = bf2f(v.z & 0xffffu); f[5] = bf2f(v.z >> 16);
  f[6] = bf2f(v.w & 0xffffu); f[7] = bf2f(v.w >> 16);
}
__device__ __forceinline__ void acc8(uint4 v, float* f) {
  f[0] += bf2f(v.x & 0xffffu); f[1] += bf2f(v.x >> 16);
  f[2] += bf2f(v.y & 0xffffu); f[3] += bf2f(v.y >> 16);
  f[4] += bf2f(v.z & 0xffffu); f[5] += bf2f(v.z >> 16);
  f[6] += bf2f(v.w & 0xffffu); f[7] += bf2f(v.w >> 16);
}
__device__ __forceinline__ uint4 pack8(const float* f) {
  uint4 v;
  v.x = f2bf(f[0]) | ((unsigned)f2bf(f[1]) << 16);
  v.y = f2bf(f[2]) | ((unsigned)f2bf(f[3]) << 16);
  v.z = f2bf(f[4]) | ((unsigned)f2bf(f[5]) << 16);
  v.w = f2bf(f[6]) | ((unsigned)f2bf(f[7]) << 16);
  return v;
}

#define SWZ(byte_, row_) ((byte_) ^ (((row_) & 7) << 4))
#define CPAD 4   // counters: 1 int per 64B line (atomic line-serialization fix)

// ---------- prep: x cvt | weights cvt pre-swizzled | degree hist (padded) ----------
#define CVT_BLK 3125
#define WCV_BLK 48
#define HIST_BLK 2500
__global__ __launch_bounds__(256) void prep_kernel(
    const float4* __restrict__ x, uint4* __restrict__ xb,
    const float* __restrict__ W1, const float* __restrict__ W2,
    uint4* __restrict__ wb, const int* __restrict__ dst,
    int* __restrict__ counts) {
  int b = blockIdx.x;
  if (b < CVT_BLK) {
    int t = b * 256 + threadIdx.x;
    float4 a = x[t * 2], bb = x[t * 2 + 1];
    float f[8] = {a.x, a.y, a.z, a.w, bb.x, bb.y, bb.z, bb.w};
    xb[t] = pack8(f);
  } else if (b < CVT_BLK + WCV_BLK) {
    int t = (b - CVT_BLK) * 256 + threadIdx.x;
    int m = t >> 11;
    int q = t & 2047;
    int byte = q * 16;
    int row = byte >> 8;
    int inner = byte & 255;
    int isrc = inner ^ ((row & 7) << 4);
    int k0 = isrc >> 1;
    const float* Wsrc = (m & 1) ? W2 : W1;
    const float* p = Wsrc + ((size_t)(m >> 1) * DD * DD + row * DD + k0);
    float4 f0 = ((const float4*)p)[0], f1 = ((const float4*)p)[1];
    float f[8] = {f0.x, f0.y, f0.z, f0.w, f1.x, f1.y, f1.z, f1.w};
    wb[(size_t)m * 2048 + q] = pack8(f);
  } else {
    int e = (b - CVT_BLK - WCV_BLK) * 256 + threadIdx.x;
    atomicAdd(&counts[dst[e] << CPAD], 1);
  }
}

// ---------- CSR scans ----------
__global__ __launch_bounds__(256) void scan1_kernel(const int* __restrict__ counts,
                                                    int* __restrict__ rp,
                                                    int* __restrict__ bsum, int n) {
  int i = blockIdx.x * 256 + threadIdx.x;
  int v = (i < n) ? counts[i << CPAD] : 0;
  int lane = threadIdx.x & 63, w = threadIdx.x >> 6;
  int s = v;
#pragma unroll
  for (int off = 1; off < 64; off <<= 1) {
    int u = __shfl_up(s, off);
    if (lane >= off) s += u;
  }
  __shared__ int ws[4];
  if (lane == 63) ws[w] = s;
  __syncthreads();
  int add = 0;
#pragma unroll
  for (int k = 0; k < 4; ++k) if (k < w) add += ws[k];
  int incl = s + add;
  if (i < n) rp[i] = incl - v;
  if (threadIdx.x == 255) bsum[blockIdx.x] = incl;
}

__global__ __launch_bounds__(256) void scan2_kernel(int* __restrict__ bsum, int nb) {
  int t = threadIdx.x;
  int v = (t < nb) ? bsum[t] : 0;
  int lane = t & 63, w = t >> 6;
  int s = v;
#pragma unroll
  for (int off = 1; off < 64; off <<= 1) {
    int u = __shfl_up(s, off);
    if (lane >= off) s += u;
  }
  __shared__ int ws[4];
  if (lane == 63) ws[w] = s;
  __syncthreads();
  int add = 0;
#pragma unroll
  for (int k = 0; k < 4; ++k) if (k < w) add += ws[k];
  int incl = s + add;
  if (t < nb) bsum[t] = incl - v;
}

__global__ __launch_bounds__(256) void scan3_kernel(int* __restrict__ rp,
                                                    int* __restrict__ cursor,
                                                    const int* __restrict__ bsum, int n) {
  int i = blockIdx.x * 256 + threadIdx.x;
  if (i < n) {
    int v = rp[i] + bsum[blockIdx.x];
    rp[i] = v;
    cursor[i << CPAD] = v;
  }
  if (i == 0) rp[n] = EE;
}

__global__ __launch_bounds__(256) void fill_kernel(const int* __restrict__ src,
                                                   const int* __restrict__ dst,
                                                   int* __restrict__ cursor,
                                                   int* __restrict__ col, int E) {
  int e = blockIdx.x * blockDim.x + threadIdx.x;
  if (e < E) {
    int p = atomicAdd(&cursor[dst[e] << CPAD], 1);
    col[p] = src[e];
  }
}

// ---------- GIN aggregation: r7-proven — 16 lanes/node, 8-deep ILP, (256,4) ----------
__global__ __launch_bounds__(256, 4) void agg_kernel(const uint4* __restrict__ xin,
                                                     const int* __restrict__ row_ptr,
                                                     const int* __restrict__ colv,
                                                     uint4* __restrict__ agg, int n) {
  int tid = blockIdx.x * 256 + threadIdx.x;
  int node = tid >> 4;
  int c = tid & 15;
  if (node >= n) return;
  float acc[8];
  unpack8(xin[(size_t)node * 16 + c], acc);
  int s = row_ptr[node], e = row_ptr[node + 1];
  int j = s;
  for (; j + 8 <= e; j += 8) {
    int i0 = colv[j],     i1 = colv[j + 1], i2 = colv[j + 2], i3 = colv[j + 3];
    int i4 = colv[j + 4], i5 = colv[j + 5], i6 = colv[j + 6], i7 = colv[j + 7];
    uint4 v0 = xin[(size_t)i0 * 16 + c];
    uint4 v1 = xin[(size_t)i1 * 16 + c];
    uint4 v2 = xin[(size_t)i2 * 16 + c];
    uint4 v3 = xin[(size_t)i3 * 16 + c];
    uint4 v4 = xin[(size_t)i4 * 16 + c];
    uint4 v5 = xin[(size_t)i5 * 16 + c];
    uint4 v6 = xin[(size_t)i6 * 16 + c];
    uint4 v7 = xin[(size_t)i7 * 16 + c];
    acc8(v0, acc); acc8(v1, acc); acc8(v2, acc); acc8(v3, acc);
    acc8(v4, acc); acc8(v5, acc); acc8(v6, acc); acc8(v7, acc);
  }
  for (; j + 2 <= e; j += 2) {
    uint4 v0 = xin[(size_t)colv[j] * 16 + c];
    uint4 v1 = xin[(size_t)colv[j + 1] * 16 + c];
    acc8(v0, acc); acc8(v1, acc);
  }
  if (j < e) acc8(xin[(size_t)colv[j] * 16 + c], acc);
  agg[(size_t)node * 16 + c] = pack8(acc);
}

// ---------- barrier-free MFMA MLP ----------
// Per-wave 16-row tiles (3125 tiles, exact). A-fragments come straight from
// global (L2-hot aggb) since a wave's A rows are its own 16 rows. LDS: shared
// W1/W2 (one barrier after staging) + 4KB wave-private scratch for the h
// transpose and output packing — wave-local LDS roundtrips, in-order DS pipe,
// NO barriers in the tile loop.
__global__ __launch_bounds__(512) void mlp_nb(
    const uint4* __restrict__ aggb, uint4* __restrict__ xout,
    const uint4* __restrict__ w1b, const uint4* __restrict__ w2b,
    const float* __restrict__ b1, const float* __restrict__ bng,
    const float* __restrict__ bnb, const float* __restrict__ bnm,
    const float* __restrict__ bnv, const float* __restrict__ b2) {
  __shared__ __align__(16) char smem[98304];
  char* w1p = smem;           // 32KB
  char* w2p = smem + 32768;   // 32KB
#pragma unroll
  for (int it = 0; it < 8; ++it) {
    int q = it * 512 + threadIdx.x;
    ((uint4*)w1p)[q] = w1b[q];
    ((uint4*)w2p)[q] = w2b[q];
  }
  int lane = threadIdx.x & 63;
  int c = lane & 15;
  int kq = lane >> 4;
  int wave = threadIdx.x >> 6;
  char* hs = smem + 65536 + wave * 4096;   // wave-private 16 rows x 256B
  __syncthreads();   // the only barrier: weights staged

  float b1v[8], sv[8], tv[8], b2v[8];
#pragma unroll
  for (int ni = 0; ni < 8; ++ni) {
    int cc = ni * 16 + c;
    b1v[ni] = b1[cc];
    float s = bng[cc] * rsqrtf(bnv[cc] + 1e-5f);
    sv[ni] = s;
    tv[ni] = bnb[cc] - bnm[cc] * s;
    b2v[ni] = b2[cc];
  }

  for (int t = blockIdx.x * 8 + wave; t < NN / 16; t += 2048) {
    int base = t * 16;
    f32x4 acc[8];
#pragma unroll
    for (int ni = 0; ni < 8; ++ni) acc[ni] = (f32x4){0.f, 0.f, 0.f, 0.f};

    // GEMM1: A direct from global (wave's own 16 rows)
#pragma unroll
    for (int ks = 0; ks < 4; ++ks) {
      bf16x8 a = *(const bf16x8*)(aggb + (size_t)(base + c) * 16 + ks * 4 + kq);
#pragma unroll
      for (int ni = 0; ni < 8; ++ni) {
        int wr = ni * 16 + c;
        bf16x8 bfr = *(const bf16x8*)(w1p + SWZ(wr * 256 + ks * 64 + kq * 16, wr));
        acc[ni] = __builtin_amdgcn_mfma_f32_16x16x32_bf16(a, bfr, acc[ni], 0, 0, 0);
      }
    }

    // epilogue 1: leaky+BN -> wave scratch (swizzled rows)
#pragma unroll
    for (int ni = 0; ni < 8; ++ni)
#pragma unroll
      for (int r = 0; r < 4; ++r) {
        float h = acc[ni][r] + b1v[ni];
        h = h >= 0.f ? h : 0.2f * h;
        h = h * sv[ni] + tv[ni];
        int row = kq * 4 + r;
        *(__bf16*)(hs + row * 256 + SWZ((ni * 16 + c) * 2, row)) = (__bf16)h;
      }

#pragma unroll
    for (int ni = 0; ni < 8; ++ni) acc[ni] = (f32x4){0.f, 0.f, 0.f, 0.f};

    // GEMM2: A from wave scratch (swizzled read; lane reads row c)
#pragma unroll
    for (int ks = 0; ks < 4; ++ks) {
      bf16x8 a = *(const bf16x8*)(hs + c * 256 + SWZ(ks * 64 + kq * 16, c));
#pragma unroll
      for (int ni = 0; ni < 8; ++ni) {
        int wr = ni * 16 + c;
        bf16x8 bfr = *(const bf16x8*)(w2p + SWZ(wr * 256 + ks * 64 + kq * 16, wr));
        acc[ni] = __builtin_amdgcn_mfma_f32_16x16x32_bf16(a, bfr, acc[ni], 0, 0, 0);
      }
    }

    // epilogue 2: leaky -> scratch (linear), then packed uint4 global stores
#pragma unroll
    for (int ni = 0; ni < 8; ++ni)
#pragma unroll
      for (int r = 0; r < 4; ++r) {
        float xo = acc[ni][r] + b2v[ni];
        xo = xo >= 0.f ? xo : 0.2f * xo;
        int row = kq * 4 + r;
        *(__bf16*)(hs + row * 256 + (ni * 16 + c) * 2) = (__bf16)xo;
      }
#pragma unroll
    for (int it2 = 0; it2 < 4; ++it2) {
      int chunk = it2 * 64 + lane;           // 0..255 = 4KB
      uint4 v = *(const uint4*)(hs + chunk * 16);
      xout[(size_t)base * 16 + chunk] = v;
    }
  }
}

// ---------- head with inline pooling (batch sorted -> per-graph range) ----------
__global__ __launch_bounds__(128) void head_kernel(
    const unsigned short* __restrict__ x, const int* __restrict__ batch,
    const float* __restrict__ og, const float* __restrict__ ob,
    const float* __restrict__ om, const float* __restrict__ ov,
    const float* __restrict__ fcW, const float* __restrict__ fcb,
    float* __restrict__ out) {
  __shared__ float pb[DD];
  __shared__ int slo, shi;
  int g = blockIdx.x;
  int t = threadIdx.x;
  if (t == 0) {
    int lo = 0, hi = NN;
    while (lo < hi) { int m = (lo + hi) >> 1; if (batch[m] < g) lo = m + 1; else hi = m; }
    slo = lo;
    lo = 0; hi = NN;
    while (lo < hi) { int m = (lo + hi) >> 1; if (batch[m] < g + 1) lo = m + 1; else hi = m; }
    shi = lo;
  }
  __syncthreads();
  float acc = 0.f;
  int node = slo;
  for (; node + 4 <= shi; node += 4) {
    float a0 = bf2f(x[(size_t)(node + 0) * DD + t]);
    float a1 = bf2f(x[(size_t)(node + 1) * DD + t]);
    float a2 = bf2f(x[(size_t)(node + 2) * DD + t]);
    float a3 = bf2f(x[(size_t)(node + 3) * DD + t]);
    acc += (a0 + a1) + (a2 + a3);
  }
  for (; node < shi; ++node) acc += bf2f(x[(size_t)node * DD + t]);
  float s = og[t] * rsqrtf(ov[t] + 1e-5f);
  pb[t] = (acc - om[t]) * s + ob[t];
  __syncthreads();
  if (t < LATD) {
    float a = fcb[t];
#pragma unroll 8
    for (int d = 0; d < DD; ++d) a = fmaf(fcW[t * DD + d], pb[d], a);
    out[(size_t)g * LATD + t] = a;
  }
}

extern "C" void kernel_launch(void* const* d_in, const int* in_sizes, int n_in,
                              void* d_out, int out_size, void* d_ws, size_t ws_size,
                              hipStream_t stream) {
  const float* x   = (const float*)d_in[0];
  const float* W1  = (const float*)d_in[1];
  const float* b1  = (const float*)d_in[2];
  const float* bng = (const float*)d_in[3];
  const float* bnb = (const float*)d_in[4];
  const float* bnm = (const float*)d_in[5];
  const float* bnv = (const float*)d_in[6];
  const float* W2  = (const float*)d_in[7];
  const float* b2  = (const float*)d_in[8];
  const float* og  = (const float*)d_in[9];
  const float* ob  = (const float*)d_in[10];
  const float* om  = (const float*)d_in[11];
  const float* ov  = (const float*)d_in[12];
  const float* fcW = (const float*)d_in[13];
  const float* fcb = (const float*)d_in[14];
  const int* ei    = (const int*)d_in[15];
  const int* batch = (const int*)d_in[16];
  const int* src  = ei;
  const int* dstp = ei + EE;

  char* ws = (char*)d_ws;
  size_t off = 0;
  auto alloc = [&](size_t bytes) {
    void* p = ws + off;
    off += (bytes + 255) & ~(size_t)255;
    return p;
  };
  unsigned short* xb0  = (unsigned short*)alloc((size_t)NN * DD * 2);
  unsigned short* xb1  = (unsigned short*)alloc((size_t)NN * DD * 2);
  unsigned short* aggb = (unsigned short*)alloc((size_t)NN * DD * 2);
  uint4* wb     = (uint4*)alloc((size_t)6 * 2048 * 16);
  int* row_ptr  = (int*)alloc((NN + 1) * 4);
  int* cursor   = (int*)alloc((size_t)NN * 64);   // padded
  int* counts   = (int*)alloc((size_t)NN * 64);   // padded
  int* col      = (int*)alloc(EE * 4);
  int* bsum     = (int*)alloc(256 * 4);

  hipMemsetAsync(counts, 0, (size_t)NN * 64, stream);

  prep_kernel<<<CVT_BLK + WCV_BLK + HIST_BLK, 256, 0, stream>>>(
      (const float4*)x, (uint4*)xb0, W1, W2, wb, dstp, counts);

  const int NB = (NN + 255) / 256;  // 196
  scan1_kernel<<<NB, 256, 0, stream>>>(counts, row_ptr, bsum, NN);
  scan2_kernel<<<1, 256, 0, stream>>>(bsum, NB);
  scan3_kernel<<<NB, 256, 0, stream>>>(row_ptr, cursor, bsum, NN);
  fill_kernel<<<(EE + 255) / 256, 256, 0, stream>>>(src, dstp, cursor, col, EE);

  unsigned short* xcur = xb0;
  unsigned short* xnext = xb1;
  for (int i = 0; i < LL; ++i) {
    agg_kernel<<<(NN * 16 + 255) / 256, 256, 0, stream>>>(
        (const uint4*)xcur, row_ptr, col, (uint4*)aggb, NN);
    mlp_nb<<<256, 512, 0, stream>>>(
        (const uint4*)aggb, (uint4*)xnext,
        wb + (size_t)i * 4096, wb + (size_t)i * 4096 + 2048,
        b1 + i * DD, bng + i * DD, bnb + i * DD, bnm + i * DD, bnv + i * DD,
        b2 + i * DD);
    unsigned short* t = xcur; xcur = xnext; xnext = t;
  }
  head_kernel<<<GG, 128, 0, stream>>>(
      xcur, batch, og, ob, om, ov, fcW, fcb, (float*)d_out);
}